// Round 1
// baseline (3399.318 us; speedup 1.0000x reference)
//
#include <hip/hip_runtime.h>

// ---------------------------------------------------------------------------
// LATTE heterogeneous GNN layer (gene/protein), fp32 baseline.
// Pipeline:
//   1. l/r node projections      : tiled fp32 GEMM  [N,256] @ [256,128] + bias
//   2. al/ar attention proj      : tiled fp32 GEMM  [N,128] @ [128,32]  + bias
//   3. edge logits + softmax den : per-edge tanh-dot + expf + atomicAdd denom
//   4. message scatter           : 32 lanes/edge, float4 gather, atomicAdd agg
//   5. relation combine          : 1 wave/node, shuffle-reduce conv dot,
//                                  softmax over relations, ReLU
// d_out is reused as agg_gg (first half) / agg_pp (second half) scratch;
// combine rewrites it in place (per-lane element ownership -> no hazard).
// ---------------------------------------------------------------------------

// ---------------- tiled fp32 GEMM: C[N,BN] = A[N,K] @ W[BN,K]^T + bias -----
template <int BM, int BN, int BK, int TM, int TN>
__global__ __launch_bounds__(256) void gemm_bias(
    const float* __restrict__ A, const float* __restrict__ W,
    const float* __restrict__ bias, float* __restrict__ Cout, int N, int K) {
  constexpr int TX = BN / TN;  // threads along cols
  constexpr int TY = BM / TM;  // threads along rows
  static_assert(TX * TY == 256, "block must be 256 threads");

  __shared__ float As[BK][BM + 4];  // +4 pad keeps float4 alignment
  __shared__ float Ws[BK][BN + 4];

  const int tid = threadIdx.x;
  const int tx = tid % TX;
  const int ty = tid / TX;
  const int rowBase = blockIdx.x * BM;

  float acc[TM][TN];
#pragma unroll
  for (int i = 0; i < TM; ++i)
#pragma unroll
    for (int j = 0; j < TN; ++j) acc[i][j] = 0.f;

  for (int k0 = 0; k0 < K; k0 += BK) {
    // stage A tile (row-guarded), coalesced along k
#pragma unroll
    for (int i = 0; i < (BM * BK) / 256; ++i) {
      int idx = tid + i * 256;
      int k = idx % BK, r = idx / BK;
      int row = rowBase + r;
      As[k][r] = (row < N) ? A[(size_t)row * K + k0 + k] : 0.f;
    }
    // stage W tile, coalesced along k
#pragma unroll
    for (int i = 0; i < (BN * BK) / 256; ++i) {
      int idx = tid + i * 256;
      int k = idx % BK, c = idx / BK;
      Ws[k][c] = W[(size_t)c * K + k0 + k];
    }
    __syncthreads();

#pragma unroll
    for (int k = 0; k < BK; ++k) {
      float a[TM], w[TN];
#pragma unroll
      for (int i = 0; i < TM; ++i) a[i] = As[k][ty * TM + i];
#pragma unroll
      for (int j = 0; j < TN; ++j) w[j] = Ws[k][tx * TN + j];
#pragma unroll
      for (int i = 0; i < TM; ++i)
#pragma unroll
        for (int j = 0; j < TN; ++j) acc[i][j] += a[i] * w[j];
    }
    __syncthreads();
  }

#pragma unroll
  for (int i = 0; i < TM; ++i) {
    int row = rowBase + ty * TM + i;
    if (row < N) {
#pragma unroll
      for (int j = 0; j < TN; ++j) {
        int col = tx * TN + j;
        Cout[(size_t)row * BN + col] = acc[i][j] + bias[col];
      }
    }
  }
}

// ------------- edge logits: e = tanh([a_i, a_j]) . qw * sharp; ex=exp(e) ---
__global__ __launch_bounds__(256) void edge_logits_kernel(
    const float* __restrict__ al, const float* __restrict__ ar,
    const int* __restrict__ src, const int* __restrict__ dst,
    const float* __restrict__ qw_mp, const float* __restrict__ sharp_mp,
    float* __restrict__ exbuf, float* __restrict__ denom, int E) {
  __shared__ float q[64];
  if (threadIdx.x < 64) q[threadIdx.x] = qw_mp[threadIdx.x];
  __syncthreads();

  int e = blockIdx.x * 256 + threadIdx.x;
  if (e >= E) return;
  int s = src[e], d = dst[e];

  const float4* a4 = (const float4*)(al + (size_t)s * 32);
  const float4* b4 = (const float4*)(ar + (size_t)d * 32);
  float acc = 0.f;
#pragma unroll
  for (int i = 0; i < 8; ++i) {
    float4 v = a4[i];
    acc += tanhf(v.x) * q[i * 4 + 0] + tanhf(v.y) * q[i * 4 + 1] +
           tanhf(v.z) * q[i * 4 + 2] + tanhf(v.w) * q[i * 4 + 3];
  }
#pragma unroll
  for (int i = 0; i < 8; ++i) {
    float4 v = b4[i];
    acc += tanhf(v.x) * q[32 + i * 4 + 0] + tanhf(v.y) * q[32 + i * 4 + 1] +
           tanhf(v.z) * q[32 + i * 4 + 2] + tanhf(v.w) * q[32 + i * 4 + 3];
  }
  // No segment-max subtraction: |acc*sharp| <= sum|qw| ~ 10, exp() is safe in
  // fp32 and alpha = ex/sum(ex) is identical to the max-shifted form.
  float ex = expf(acc * sharp_mp[0]);
  exbuf[e] = ex;
  atomicAdd(&denom[s], ex);
}

// ------------- scatter messages: agg[src] += r_tail[dst] * alpha -----------
__global__ __launch_bounds__(256) void scatter_kernel(
    const float* __restrict__ rtail, const int* __restrict__ src,
    const int* __restrict__ dst, const float* __restrict__ exbuf,
    const float* __restrict__ denom, float* __restrict__ agg, int E) {
  int gid = blockIdx.x * 256 + threadIdx.x;
  int e = gid >> 5;   // 32 lanes per edge
  int l = gid & 31;   // 4 floats each
  if (e >= E) return;
  int s = src[e], d = dst[e];
  float alpha = exbuf[e] / (denom[s] + 1e-16f);
  float4 v = *(const float4*)(rtail + (size_t)d * 128 + l * 4);
  float* p = agg + (size_t)s * 128 + l * 4;
  atomicAdd(p + 0, v.x * alpha);
  atomicAdd(p + 1, v.y * alpha);
  atomicAdd(p + 2, v.z * alpha);
  atomicAdd(p + 3, v.w * alpha);
}

// ------------- relation combine: softmax over R relations, ReLU ------------
template <int R>
__global__ __launch_bounds__(256) void combine_kernel(
    const float* __restrict__ rel0, const float* __restrict__ rel1,
    const float* __restrict__ rel2, const float* __restrict__ convW,
    const float* __restrict__ convb, float* __restrict__ out, int N) {
  int lane = threadIdx.x & 63;
  int node = blockIdx.x * 4 + (threadIdx.x >> 6);
  if (node >= N) return;
  int c = lane * 2;
  const float w0 = convW[c], w1 = convW[c + 1];
  const float* rels[3] = {rel0, rel1, rel2};

  float2 v[R];
  float s[R];
#pragma unroll
  for (int r = 0; r < R; ++r) {
    float2 t = *(const float2*)(rels[r] + (size_t)node * 128 + c);
    v[r] = t;
    float p = t.x * w0 + t.y * w1;
#pragma unroll
    for (int m = 32; m >= 1; m >>= 1) p += __shfl_xor(p, m, 64);
    s[r] = p + convb[0];
  }
  float mx = s[0];
#pragma unroll
  for (int r = 1; r < R; ++r) mx = fmaxf(mx, s[r]);
  float es[R], sum = 0.f;
#pragma unroll
  for (int r = 0; r < R; ++r) {
    es[r] = expf(s[r] - mx);
    sum += es[r];
  }
  float ox = 0.f, oy = 0.f;
#pragma unroll
  for (int r = 0; r < R; ++r) {
    float b = es[r] / sum;
    ox += v[r].x * b;
    oy += v[r].y * b;
  }
  float2 o = make_float2(fmaxf(ox, 0.f), fmaxf(oy, 0.f));
  *(float2*)(out + (size_t)node * 128 + c) = o;
}

// ---------------------------------------------------------------------------
extern "C" void kernel_launch(void* const* d_in, const int* in_sizes, int n_in,
                              void* d_out, int out_size, void* d_ws,
                              size_t ws_size, hipStream_t stream) {
  const float* x_gene  = (const float*)d_in[0];
  const float* x_prot  = (const float*)d_in[1];
  const float* Wl_gene = (const float*)d_in[2];
  const float* bl_gene = (const float*)d_in[3];
  const float* Wr_gene = (const float*)d_in[4];
  const float* br_gene = (const float*)d_in[5];
  const float* Wl_prot = (const float*)d_in[6];
  const float* bl_prot = (const float*)d_in[7];
  const float* Wr_prot = (const float*)d_in[8];
  const float* br_prot = (const float*)d_in[9];
  const float* alW     = (const float*)d_in[10];  // [3,32,128]
  const float* alb     = (const float*)d_in[11];  // [3,32]
  const float* arW     = (const float*)d_in[12];
  const float* arb     = (const float*)d_in[13];
  const float* qw      = (const float*)d_in[14];  // [3,64,1]
  const float* sharp   = (const float*)d_in[15];  // [3]
  const float* cgW     = (const float*)d_in[16];
  const float* cgb     = (const float*)d_in[17];
  const float* cpW     = (const float*)d_in[18];
  const float* cpb     = (const float*)d_in[19];
  const int* e_gg      = (const int*)d_in[20];    // [2,E] row0=head, row1=tail
  const int* e_gp      = (const int*)d_in[21];
  const int* e_pp      = (const int*)d_in[22];

  const int NG = in_sizes[0] / 256;   // 50000
  const int NP = in_sizes[1] / 256;   // 50000
  const int E  = in_sizes[20] / 2;    // 500000

  // workspace layout (floats)
  float* ws = (float*)d_ws;
  float* l_gene = ws;
  float* r_gene = l_gene + (size_t)NG * 128;
  float* l_prot = r_gene + (size_t)NG * 128;
  float* r_prot = l_prot + (size_t)NP * 128;
  float* agg_gp = r_prot + (size_t)NP * 128;
  float* al_buf = agg_gp + (size_t)NG * 128;
  float* ar_buf = al_buf + (size_t)NG * 32;
  float* ex_buf = ar_buf + (size_t)NG * 32;
  float* denom  = ex_buf + (size_t)E;

  float* out_gene = (float*)d_out;                 // doubles as agg_gg
  float* out_prot = out_gene + (size_t)NG * 128;   // doubles as agg_pp

  dim3 blk(256);
  const int gridG = (NG + 63) / 64;
  const int gridP = (NP + 63) / 64;
  const int gridE = (E + 255) / 256;
  const int gridS = (E * 32 + 255) / 256;

  // zero accumulation targets (d_out & ws are re-poisoned before every call)
  hipMemsetAsync(d_out, 0, (size_t)(NG + NP) * 128 * sizeof(float), stream);
  hipMemsetAsync(agg_gp, 0, (size_t)NG * 128 * sizeof(float), stream);

  // 1) l/r projections
  gemm_bias<64, 128, 32, 4, 8><<<gridG, blk, 0, stream>>>(x_gene, Wl_gene, bl_gene, l_gene, NG, 256);
  gemm_bias<64, 128, 32, 4, 8><<<gridG, blk, 0, stream>>>(x_gene, Wr_gene, br_gene, r_gene, NG, 256);
  gemm_bias<64, 128, 32, 4, 8><<<gridP, blk, 0, stream>>>(x_prot, Wl_prot, bl_prot, l_prot, NP, 256);
  gemm_bias<64, 128, 32, 4, 8><<<gridP, blk, 0, stream>>>(x_prot, Wr_prot, br_prot, r_prot, NP, 256);

  // 2-4) per metapath: attention proj, logits+denominator, scatter
  // mp0: gene <- gene, agg into out_gene
  gemm_bias<64, 32, 32, 4, 2><<<gridG, blk, 0, stream>>>(l_gene, alW + 0 * 4096, alb + 0 * 32, al_buf, NG, 128);
  gemm_bias<64, 32, 32, 4, 2><<<gridG, blk, 0, stream>>>(r_gene, arW + 0 * 4096, arb + 0 * 32, ar_buf, NG, 128);
  hipMemsetAsync(denom, 0, (size_t)NG * sizeof(float), stream);
  edge_logits_kernel<<<gridE, blk, 0, stream>>>(al_buf, ar_buf, e_gg, e_gg + E, qw + 0 * 64, sharp + 0, ex_buf, denom, E);
  scatter_kernel<<<gridS, blk, 0, stream>>>(r_gene, e_gg, e_gg + E, ex_buf, denom, out_gene, E);

  // mp1: gene <- protein, agg into agg_gp
  gemm_bias<64, 32, 32, 4, 2><<<gridG, blk, 0, stream>>>(l_gene, alW + 1 * 4096, alb + 1 * 32, al_buf, NG, 128);
  gemm_bias<64, 32, 32, 4, 2><<<gridP, blk, 0, stream>>>(r_prot, arW + 1 * 4096, arb + 1 * 32, ar_buf, NP, 128);
  hipMemsetAsync(denom, 0, (size_t)NG * sizeof(float), stream);
  edge_logits_kernel<<<gridE, blk, 0, stream>>>(al_buf, ar_buf, e_gp, e_gp + E, qw + 1 * 64, sharp + 1, ex_buf, denom, E);
  scatter_kernel<<<gridS, blk, 0, stream>>>(r_prot, e_gp, e_gp + E, ex_buf, denom, agg_gp, E);

  // mp2: protein <- protein, agg into out_prot
  gemm_bias<64, 32, 32, 4, 2><<<gridP, blk, 0, stream>>>(l_prot, alW + 2 * 4096, alb + 2 * 32, al_buf, NP, 128);
  gemm_bias<64, 32, 32, 4, 2><<<gridP, blk, 0, stream>>>(r_prot, arW + 2 * 4096, arb + 2 * 32, ar_buf, NP, 128);
  hipMemsetAsync(denom, 0, (size_t)NP * sizeof(float), stream);
  edge_logits_kernel<<<gridE, blk, 0, stream>>>(al_buf, ar_buf, e_pp, e_pp + E, qw + 2 * 64, sharp + 2, ex_buf, denom, E);
  scatter_kernel<<<gridS, blk, 0, stream>>>(r_prot, e_pp, e_pp + E, ex_buf, denom, out_prot, E);

  // 5) relation combine (in-place over d_out)
  combine_kernel<3><<<(NG + 3) / 4, blk, 0, stream>>>(out_gene, agg_gp, l_gene, cgW, cgb, out_gene, NG);
  combine_kernel<2><<<(NP + 3) / 4, blk, 0, stream>>>(out_prot, l_prot, nullptr, cpW, cpb, out_prot, NP);
}

// Round 2
// 1359.631 us; speedup vs baseline: 2.5002x; 2.5002x over previous
//
#include <hip/hip_runtime.h>

// ---------------------------------------------------------------------------
// LATTE heterogeneous GNN layer (gene/protein), fp32, CSR aggregation.
// Pipeline per metapath:
//   hist -> prefix-scan -> logits+sorted-scatter(dst,ex) -> wave-per-node
//   gather (shuffle-reduce denom, register accumulate, single store).
// No atomics in the message-aggregation hot path.
// ---------------------------------------------------------------------------

// ---------------- tiled fp32 GEMM: C[N,BN] = A[N,K] @ W[BN,K]^T + bias -----
template <int BM, int BN, int BK, int TM, int TN>
__global__ __launch_bounds__(256) void gemm_bias(
    const float* __restrict__ A, const float* __restrict__ W,
    const float* __restrict__ bias, float* __restrict__ Cout, int N, int K) {
  constexpr int TX = BN / TN;
  constexpr int TY = BM / TM;
  static_assert(TX * TY == 256, "block must be 256 threads");

  __shared__ float As[BK][BM + 4];
  __shared__ float Ws[BK][BN + 4];

  const int tid = threadIdx.x;
  const int tx = tid % TX;
  const int ty = tid / TX;
  const int rowBase = blockIdx.x * BM;

  float acc[TM][TN];
#pragma unroll
  for (int i = 0; i < TM; ++i)
#pragma unroll
    for (int j = 0; j < TN; ++j) acc[i][j] = 0.f;

  for (int k0 = 0; k0 < K; k0 += BK) {
#pragma unroll
    for (int i = 0; i < (BM * BK) / 256; ++i) {
      int idx = tid + i * 256;
      int k = idx % BK, r = idx / BK;
      int row = rowBase + r;
      As[k][r] = (row < N) ? A[(size_t)row * K + k0 + k] : 0.f;
    }
#pragma unroll
    for (int i = 0; i < (BN * BK) / 256; ++i) {
      int idx = tid + i * 256;
      int k = idx % BK, c = idx / BK;
      Ws[k][c] = W[(size_t)c * K + k0 + k];
    }
    __syncthreads();

#pragma unroll
    for (int k = 0; k < BK; ++k) {
      float a[TM], w[TN];
#pragma unroll
      for (int i = 0; i < TM; ++i) a[i] = As[k][ty * TM + i];
#pragma unroll
      for (int j = 0; j < TN; ++j) w[j] = Ws[k][tx * TN + j];
#pragma unroll
      for (int i = 0; i < TM; ++i)
#pragma unroll
        for (int j = 0; j < TN; ++j) acc[i][j] += a[i] * w[j];
    }
    __syncthreads();
  }

#pragma unroll
  for (int i = 0; i < TM; ++i) {
    int row = rowBase + ty * TM + i;
    if (row < N) {
#pragma unroll
      for (int j = 0; j < TN; ++j) {
        int col = tx * TN + j;
        Cout[(size_t)row * BN + col] = acc[i][j] + bias[col];
      }
    }
  }
}

// ---------------- degree histogram ----------------------------------------
__global__ __launch_bounds__(256) void hist_kernel(
    const int* __restrict__ src, int* __restrict__ deg, int E) {
  int e = blockIdx.x * 256 + threadIdx.x;
  if (e < E) atomicAdd(&deg[src[e]], 1);
}

// ---------------- single-block exclusive prefix sum -----------------------
__global__ __launch_bounds__(1024) void scan_kernel(
    const int* __restrict__ deg, int* __restrict__ offsets, int n) {
  __shared__ int buf[1024];
  __shared__ int carry;
  if (threadIdx.x == 0) {
    carry = 0;
    offsets[0] = 0;
  }
  __syncthreads();
  for (int base = 0; base < n; base += 1024) {
    int i = base + threadIdx.x;
    int v = (i < n) ? deg[i] : 0;
    buf[threadIdx.x] = v;
    __syncthreads();
#pragma unroll
    for (int off = 1; off < 1024; off <<= 1) {
      int t = (threadIdx.x >= off) ? buf[threadIdx.x - off] : 0;
      __syncthreads();
      buf[threadIdx.x] += t;
      __syncthreads();
    }
    int c = carry;
    if (i < n) offsets[i + 1] = c + buf[threadIdx.x];
    __syncthreads();
    if (threadIdx.x == 0) carry = c + buf[1023];
    __syncthreads();
  }
}

// ------- edge logits + sorted scatter: ex_s/dst_s in CSR order ------------
__global__ __launch_bounds__(256) void edge_logits_scatter(
    const float* __restrict__ al, const float* __restrict__ ar,
    const int* __restrict__ src, const int* __restrict__ dst,
    const float* __restrict__ qw_mp, const float* __restrict__ sharp_mp,
    const int* __restrict__ offsets, int* __restrict__ cnt,
    int* __restrict__ dst_s, float* __restrict__ ex_s, int E) {
  __shared__ float q[64];
  if (threadIdx.x < 64) q[threadIdx.x] = qw_mp[threadIdx.x];
  __syncthreads();

  int e = blockIdx.x * 256 + threadIdx.x;
  if (e >= E) return;
  int s = src[e], d = dst[e];

  const float4* a4 = (const float4*)(al + (size_t)s * 32);
  const float4* b4 = (const float4*)(ar + (size_t)d * 32);
  float acc = 0.f;
#pragma unroll
  for (int i = 0; i < 8; ++i) {
    float4 v = a4[i];
    acc += tanhf(v.x) * q[i * 4 + 0] + tanhf(v.y) * q[i * 4 + 1] +
           tanhf(v.z) * q[i * 4 + 2] + tanhf(v.w) * q[i * 4 + 3];
  }
#pragma unroll
  for (int i = 0; i < 8; ++i) {
    float4 v = b4[i];
    acc += tanhf(v.x) * q[32 + i * 4 + 0] + tanhf(v.y) * q[32 + i * 4 + 1] +
           tanhf(v.z) * q[32 + i * 4 + 2] + tanhf(v.w) * q[32 + i * 4 + 3];
  }
  // |acc*sharp| <= sum|qw| ~ 10 -> exp safe in fp32 without max-shift;
  // alpha = ex / sum(ex) identical to the shifted form.
  float ex = expf(acc * sharp_mp[0]);
  int pos = offsets[s] + atomicAdd(&cnt[s], 1);
  dst_s[pos] = d;
  ex_s[pos] = ex;
}

// ------- gather: one 64-lane wave per head node, no atomics ---------------
__global__ __launch_bounds__(256) void gather_kernel(
    const float* __restrict__ rtail, const int* __restrict__ offsets,
    const int* __restrict__ dst_s, const float* __restrict__ ex_s,
    float* __restrict__ agg, int N) {
  int lane = threadIdx.x & 63;
  int node = blockIdx.x * 4 + (threadIdx.x >> 6);
  if (node >= N) return;
  int j0 = offsets[node], j1 = offsets[node + 1];

  // denominator: lane-strided sum + butterfly reduce
  float dsum = 0.f;
  for (int j = j0 + lane; j < j1; j += 64) dsum += ex_s[j];
#pragma unroll
  for (int m = 32; m >= 1; m >>= 1) dsum += __shfl_xor(dsum, m, 64);
  float inv = 1.f / (dsum + 1e-16f);

  float2 acc = make_float2(0.f, 0.f);
  for (int j = j0; j < j1; ++j) {
    int d = dst_s[j];             // wave-uniform broadcast load
    float w = ex_s[j] * inv;
    float2 v = *(const float2*)(rtail + (size_t)d * 128 + lane * 2);
    acc.x += v.x * w;
    acc.y += v.y * w;
  }
  *(float2*)(agg + (size_t)node * 128 + lane * 2) = acc;
}

// ------------- relation combine: softmax over R relations, ReLU ------------
template <int R>
__global__ __launch_bounds__(256) void combine_kernel(
    const float* __restrict__ rel0, const float* __restrict__ rel1,
    const float* __restrict__ rel2, const float* __restrict__ convW,
    const float* __restrict__ convb, float* __restrict__ out, int N) {
  int lane = threadIdx.x & 63;
  int node = blockIdx.x * 4 + (threadIdx.x >> 6);
  if (node >= N) return;
  int c = lane * 2;
  const float w0 = convW[c], w1 = convW[c + 1];
  const float* rels[3] = {rel0, rel1, rel2};

  float2 v[R];
  float s[R];
#pragma unroll
  for (int r = 0; r < R; ++r) {
    float2 t = *(const float2*)(rels[r] + (size_t)node * 128 + c);
    v[r] = t;
    float p = t.x * w0 + t.y * w1;
#pragma unroll
    for (int m = 32; m >= 1; m >>= 1) p += __shfl_xor(p, m, 64);
    s[r] = p + convb[0];
  }
  float mx = s[0];
#pragma unroll
  for (int r = 1; r < R; ++r) mx = fmaxf(mx, s[r]);
  float es[R], sum = 0.f;
#pragma unroll
  for (int r = 0; r < R; ++r) {
    es[r] = expf(s[r] - mx);
    sum += es[r];
  }
  float ox = 0.f, oy = 0.f;
#pragma unroll
  for (int r = 0; r < R; ++r) {
    float b = es[r] / sum;
    ox += v[r].x * b;
    oy += v[r].y * b;
  }
  float2 o = make_float2(fmaxf(ox, 0.f), fmaxf(oy, 0.f));
  *(float2*)(out + (size_t)node * 128 + c) = o;
}

// ---------------------------------------------------------------------------
extern "C" void kernel_launch(void* const* d_in, const int* in_sizes, int n_in,
                              void* d_out, int out_size, void* d_ws,
                              size_t ws_size, hipStream_t stream) {
  const float* x_gene  = (const float*)d_in[0];
  const float* x_prot  = (const float*)d_in[1];
  const float* Wl_gene = (const float*)d_in[2];
  const float* bl_gene = (const float*)d_in[3];
  const float* Wr_gene = (const float*)d_in[4];
  const float* br_gene = (const float*)d_in[5];
  const float* Wl_prot = (const float*)d_in[6];
  const float* bl_prot = (const float*)d_in[7];
  const float* Wr_prot = (const float*)d_in[8];
  const float* br_prot = (const float*)d_in[9];
  const float* alW     = (const float*)d_in[10];  // [3,32,128]
  const float* alb     = (const float*)d_in[11];  // [3,32]
  const float* arW     = (const float*)d_in[12];
  const float* arb     = (const float*)d_in[13];
  const float* qw      = (const float*)d_in[14];  // [3,64,1]
  const float* sharp   = (const float*)d_in[15];  // [3]
  const float* cgW     = (const float*)d_in[16];
  const float* cgb     = (const float*)d_in[17];
  const float* cpW     = (const float*)d_in[18];
  const float* cpb     = (const float*)d_in[19];
  const int* e_gg      = (const int*)d_in[20];    // [2,E] row0=head, row1=tail
  const int* e_gp      = (const int*)d_in[21];
  const int* e_pp      = (const int*)d_in[22];

  const int NG = in_sizes[0] / 256;   // 50000
  const int NP = in_sizes[1] / 256;   // 50000
  const int E  = in_sizes[20] / 2;    // 500000

  // workspace layout (floats)
  float* ws = (float*)d_ws;
  float* l_gene = ws;
  float* r_gene = l_gene + (size_t)NG * 128;
  float* l_prot = r_gene + (size_t)NG * 128;
  float* r_prot = l_prot + (size_t)NP * 128;
  float* agg_gp = r_prot + (size_t)NP * 128;
  float* al_buf = agg_gp + (size_t)NG * 128;
  float* ar_buf = al_buf + (size_t)NG * 32;
  // CSR scratch (ints/floats), reused across metapaths (stream-serialized)
  int*   deg     = (int*)(ar_buf + (size_t)NG * 32);
  int*   cnt     = deg + NG;           // deg/cnt contiguous -> one memset
  int*   offsets = cnt + NG;
  int*   dst_s   = offsets + (NG + 1);
  float* ex_s    = (float*)(dst_s + E);

  float* out_gene = (float*)d_out;                 // holds agg_gg then result
  float* out_prot = out_gene + (size_t)NG * 128;   // holds agg_pp then result

  dim3 blk(256);
  const int gridG = (NG + 63) / 64;
  const int gridP = (NP + 63) / 64;
  const int gridE = (E + 255) / 256;
  const int gridNG = (NG + 3) / 4;
  const int gridNP = (NP + 3) / 4;

  // 1) l/r projections
  gemm_bias<64, 128, 32, 4, 8><<<gridG, blk, 0, stream>>>(x_gene, Wl_gene, bl_gene, l_gene, NG, 256);
  gemm_bias<64, 128, 32, 4, 8><<<gridG, blk, 0, stream>>>(x_gene, Wr_gene, br_gene, r_gene, NG, 256);
  gemm_bias<64, 128, 32, 4, 8><<<gridP, blk, 0, stream>>>(x_prot, Wl_prot, bl_prot, l_prot, NP, 256);
  gemm_bias<64, 128, 32, 4, 8><<<gridP, blk, 0, stream>>>(x_prot, Wr_prot, br_prot, r_prot, NP, 256);

  // ---- mp0: gene <- gene, agg into out_gene ----
  gemm_bias<64, 32, 32, 4, 2><<<gridG, blk, 0, stream>>>(l_gene, alW + 0 * 4096, alb + 0 * 32, al_buf, NG, 128);
  gemm_bias<64, 32, 32, 4, 2><<<gridG, blk, 0, stream>>>(r_gene, arW + 0 * 4096, arb + 0 * 32, ar_buf, NG, 128);
  hipMemsetAsync(deg, 0, 2 * (size_t)NG * sizeof(int), stream);
  hist_kernel<<<gridE, blk, 0, stream>>>(e_gg, deg, E);
  scan_kernel<<<1, 1024, 0, stream>>>(deg, offsets, NG);
  edge_logits_scatter<<<gridE, blk, 0, stream>>>(al_buf, ar_buf, e_gg, e_gg + E, qw + 0 * 64, sharp + 0,
                                                 offsets, cnt, dst_s, ex_s, E);
  gather_kernel<<<gridNG, blk, 0, stream>>>(r_gene, offsets, dst_s, ex_s, out_gene, NG);

  // ---- mp1: gene <- protein, agg into agg_gp ----
  gemm_bias<64, 32, 32, 4, 2><<<gridG, blk, 0, stream>>>(l_gene, alW + 1 * 4096, alb + 1 * 32, al_buf, NG, 128);
  gemm_bias<64, 32, 32, 4, 2><<<gridP, blk, 0, stream>>>(r_prot, arW + 1 * 4096, arb + 1 * 32, ar_buf, NP, 128);
  hipMemsetAsync(deg, 0, 2 * (size_t)NG * sizeof(int), stream);
  hist_kernel<<<gridE, blk, 0, stream>>>(e_gp, deg, E);
  scan_kernel<<<1, 1024, 0, stream>>>(deg, offsets, NG);
  edge_logits_scatter<<<gridE, blk, 0, stream>>>(al_buf, ar_buf, e_gp, e_gp + E, qw + 1 * 64, sharp + 1,
                                                 offsets, cnt, dst_s, ex_s, E);
  gather_kernel<<<gridNG, blk, 0, stream>>>(r_prot, offsets, dst_s, ex_s, agg_gp, NG);

  // ---- mp2: protein <- protein, agg into out_prot ----
  gemm_bias<64, 32, 32, 4, 2><<<gridP, blk, 0, stream>>>(l_prot, alW + 2 * 4096, alb + 2 * 32, al_buf, NP, 128);
  gemm_bias<64, 32, 32, 4, 2><<<gridP, blk, 0, stream>>>(r_prot, arW + 2 * 4096, arb + 2 * 32, ar_buf, NP, 128);
  hipMemsetAsync(deg, 0, 2 * (size_t)NP * sizeof(int), stream);
  hist_kernel<<<gridE, blk, 0, stream>>>(e_pp, deg, E);
  scan_kernel<<<1, 1024, 0, stream>>>(deg, offsets, NP);
  edge_logits_scatter<<<gridE, blk, 0, stream>>>(al_buf, ar_buf, e_pp, e_pp + E, qw + 2 * 64, sharp + 2,
                                                 offsets, cnt, dst_s, ex_s, E);
  gather_kernel<<<gridNP, blk, 0, stream>>>(r_prot, offsets, dst_s, ex_s, out_prot, NP);

  // 5) relation combine (in-place over d_out)
  combine_kernel<3><<<gridNG, blk, 0, stream>>>(out_gene, agg_gp, l_gene, cgW, cgb, out_gene, NG);
  combine_kernel<2><<<gridNP, blk, 0, stream>>>(out_prot, l_prot, nullptr, cpW, cpb, out_prot, NP);
}

// Round 4
// 892.974 us; speedup vs baseline: 3.8067x; 1.5226x over previous
//
#include <hip/hip_runtime.h>
#include <hip/hip_bf16.h>

// ---------------------------------------------------------------------------
// LATTE heterogeneous GNN layer (gene/protein).
// R4: same as R3 (bf16 MFMA projections + CSR aggregation) with the deg/cnt
// zeroing bug fixed: deg and cnt now share one allocation so the single
// memset covers both (R3's aligned allocator left 48 poisoned cnt entries
// -> OOB scatter -> abort).
// ---------------------------------------------------------------------------

typedef __attribute__((ext_vector_type(8))) short short8;   // 8 bf16
typedef __attribute__((ext_vector_type(4))) float floatx4;  // 4 f32 acc

__device__ __forceinline__ void gload16(const void* g, void* l) {
  __builtin_amdgcn_global_load_lds(
      (const __attribute__((address_space(1))) void*)g,
      (__attribute__((address_space(3))) void*)l, 16, 0, 0);
}

__device__ __forceinline__ ushort f2b(float x) {
  __hip_bfloat16 h = __float2bfloat16(x);
  return *reinterpret_cast<ushort*>(&h);
}
__device__ __forceinline__ float b2f_lo(unsigned v) { return __uint_as_float(v << 16); }
__device__ __forceinline__ float b2f_hi(unsigned v) { return __uint_as_float(v & 0xffff0000u); }

// ---------------- fp32 -> bf16 convert (with zero row padding) -------------
__global__ __launch_bounds__(256) void cvt_bf16_kernel(
    const float* __restrict__ src, ushort* __restrict__ dst, int valid, int total) {
  int i = (blockIdx.x * 256 + threadIdx.x) * 4;
  if (i >= total) return;
  float4 v = make_float4(0.f, 0.f, 0.f, 0.f);
  if (i < valid) v = *(const float4*)(src + i);
  ushort4 o;
  o.x = f2b(v.x); o.y = f2b(v.y); o.z = f2b(v.z); o.w = f2b(v.w);
  *(ushort4*)(dst + i) = o;
}

// ------------- fused l/r projection: [NPAD,256]bf16 @ [256,256]^T ----------
// Wb rows 0-127 = Wl, 128-255 = Wr. blockIdx.y selects half. Outputs bf16.
__global__ __launch_bounds__(256) void proj_lr_mfma(
    const ushort* __restrict__ xb, const ushort* __restrict__ Wb,
    const float* __restrict__ bl, const float* __restrict__ br,
    ushort* __restrict__ lb, ushort* __restrict__ rb, int N) {
  __shared__ ushort As[128 * 32];
  __shared__ ushort Bs[128 * 32];
  const int tid = threadIdx.x;
  const int lane = tid & 63;
  const int wave = tid >> 6;
  const int wm = wave & 1, wn = wave >> 1;
  const int rowBase = blockIdx.x * 128;
  const int colHalf = blockIdx.y;
  const ushort* Wbase = Wb + (size_t)colHalf * 128 * 256;

  floatx4 acc[4][4] = {};

  const int srow = tid >> 2, schk = tid & 3;  // staging coords (16B chunks)
  for (int k0 = 0; k0 < 256; k0 += 32) {
#pragma unroll
    for (int i = 0; i < 2; ++i) {
      gload16(xb + (size_t)(rowBase + srow + i * 64) * 256 + k0 + schk * 8,
              &As[(tid + i * 256) * 8]);
      gload16(Wbase + (size_t)(srow + i * 64) * 256 + k0 + schk * 8,
              &Bs[(tid + i * 256) * 8]);
    }
    __syncthreads();
    short8 bf[4];
#pragma unroll
    for (int nt = 0; nt < 4; ++nt)
      bf[nt] = *(const short8*)&Bs[(wn * 64 + nt * 16 + (lane & 15)) * 32 + (lane >> 4) * 8];
#pragma unroll
    for (int mt = 0; mt < 4; ++mt) {
      short8 a = *(const short8*)&As[(wm * 64 + mt * 16 + (lane & 15)) * 32 + (lane >> 4) * 8];
#pragma unroll
      for (int nt = 0; nt < 4; ++nt)
        acc[mt][nt] = __builtin_amdgcn_mfma_f32_16x16x32_bf16(a, bf[nt], acc[mt][nt], 0, 0, 0);
    }
    __syncthreads();
  }

  const float* bias = colHalf ? br : bl;
  ushort* outp = colHalf ? rb : lb;
#pragma unroll
  for (int mt = 0; mt < 4; ++mt)
#pragma unroll
    for (int nt = 0; nt < 4; ++nt) {
      int col = wn * 64 + nt * 16 + (lane & 15);
      float bv = bias[col];
#pragma unroll
      for (int vi = 0; vi < 4; ++vi) {
        int row = rowBase + wm * 64 + mt * 16 + (lane >> 4) * 4 + vi;
        if (row < N) outp[(size_t)row * 128 + col] = f2b(acc[mt][nt][vi] + bv);
      }
    }
}

// ------------- attention projection: [NPAD,128]bf16 @ [BN,128]^T -> f32 ----
template <int BN>
__global__ __launch_bounds__(256) void attn_proj_mfma(
    const ushort* __restrict__ Ab, const ushort* __restrict__ Wb,
    const float* __restrict__ bias, float* __restrict__ out, int N) {
  __shared__ ushort As[128 * 32];
  __shared__ ushort Ws[BN * 128];
  const int tid = threadIdx.x;
  const int lane = tid & 63;
  const int wave = tid >> 6;
  const int rowBase = blockIdx.x * 128;

  // whole W tile resident (flat contiguous copy)
#pragma unroll
  for (int i = 0; i < (BN * 16) / 256; ++i) {
    int idx = tid + i * 256;
    gload16(Wb + (size_t)idx * 8, &Ws[idx * 8]);
  }

  floatx4 acc[2][BN / 16] = {};
  for (int k0 = 0; k0 < 128; k0 += 32) {
#pragma unroll
    for (int i = 0; i < 2; ++i) {
      int t = tid + i * 256;
      gload16(Ab + (size_t)(rowBase + (t >> 2)) * 128 + k0 + (t & 3) * 8, &As[t * 8]);
    }
    __syncthreads();
    short8 bf[BN / 16];
#pragma unroll
    for (int nt = 0; nt < BN / 16; ++nt)
      bf[nt] = *(const short8*)&Ws[(nt * 16 + (lane & 15)) * 128 + k0 + (lane >> 4) * 8];
#pragma unroll
    for (int mt = 0; mt < 2; ++mt) {
      short8 a = *(const short8*)&As[(wave * 32 + mt * 16 + (lane & 15)) * 32 + (lane >> 4) * 8];
#pragma unroll
      for (int nt = 0; nt < BN / 16; ++nt)
        acc[mt][nt] = __builtin_amdgcn_mfma_f32_16x16x32_bf16(a, bf[nt], acc[mt][nt], 0, 0, 0);
    }
    __syncthreads();
  }
#pragma unroll
  for (int mt = 0; mt < 2; ++mt)
#pragma unroll
    for (int nt = 0; nt < BN / 16; ++nt) {
      int col = nt * 16 + (lane & 15);
      float bv = bias[col];
#pragma unroll
      for (int vi = 0; vi < 4; ++vi) {
        int row = rowBase + wave * 32 + mt * 16 + (lane >> 4) * 4 + vi;
        if (row < N) out[(size_t)row * BN + col] = acc[mt][nt][vi] + bv;
      }
    }
}

// ---------------- degree histogram ----------------------------------------
__global__ __launch_bounds__(256) void hist_kernel(
    const int* __restrict__ src, int* __restrict__ deg, int E) {
  int e = blockIdx.x * 256 + threadIdx.x;
  if (e < E) atomicAdd(&deg[src[e]], 1);
}

// ---------------- single-block prefix sum (wave-shuffle) ------------------
__global__ __launch_bounds__(1024) void scan_kernel(
    const int* __restrict__ deg, int* __restrict__ offsets, int n) {
  __shared__ int wsum[16];
  __shared__ int carry_s;
  const int lane = threadIdx.x & 63, wv = threadIdx.x >> 6;
  if (threadIdx.x == 0) { carry_s = 0; offsets[0] = 0; }
  __syncthreads();
  for (int base = 0; base < n; base += 1024) {
    int i = base + threadIdx.x;
    int x = (i < n) ? deg[i] : 0;
#pragma unroll
    for (int off = 1; off < 64; off <<= 1) {
      int t = __shfl_up(x, off, 64);
      if (lane >= off) x += t;
    }
    if (lane == 63) wsum[wv] = x;
    __syncthreads();
    int c = carry_s;
    int wpre = 0;
#pragma unroll
    for (int j = 0; j < 16; ++j) wpre += (j < wv) ? wsum[j] : 0;
    int incl = c + wpre + x;
    if (i < n) offsets[i + 1] = incl;
    __syncthreads();
    if (threadIdx.x == 1023) carry_s = incl;
    __syncthreads();
  }
}

// ------- edge logits + sorted scatter: ex_s/dst_s in CSR order ------------
__global__ __launch_bounds__(256) void edge_logits_scatter(
    const float* __restrict__ al, int als, const float* __restrict__ ar, int ars,
    const int* __restrict__ src, const int* __restrict__ dst,
    const float* __restrict__ qw_mp, const float* __restrict__ sharp_mp,
    const int* __restrict__ offsets, int* __restrict__ cnt,
    int* __restrict__ dst_s, float* __restrict__ ex_s, int E) {
  __shared__ float q[64];
  if (threadIdx.x < 64) q[threadIdx.x] = qw_mp[threadIdx.x];
  __syncthreads();

  int e = blockIdx.x * 256 + threadIdx.x;
  if (e >= E) return;
  int s = src[e], d = dst[e];

  const float4* a4 = (const float4*)(al + (size_t)s * als);
  const float4* b4 = (const float4*)(ar + (size_t)d * ars);
  float acc = 0.f;
#pragma unroll
  for (int i = 0; i < 8; ++i) {
    float4 v = a4[i];
    acc += tanhf(v.x) * q[i * 4 + 0] + tanhf(v.y) * q[i * 4 + 1] +
           tanhf(v.z) * q[i * 4 + 2] + tanhf(v.w) * q[i * 4 + 3];
  }
#pragma unroll
  for (int i = 0; i < 8; ++i) {
    float4 v = b4[i];
    acc += tanhf(v.x) * q[32 + i * 4 + 0] + tanhf(v.y) * q[32 + i * 4 + 1] +
           tanhf(v.z) * q[32 + i * 4 + 2] + tanhf(v.w) * q[32 + i * 4 + 3];
  }
  // |acc*sharp| <= sum|qw| ~ 10 -> exp safe in fp32 without max-shift.
  float ex = expf(acc * sharp_mp[0]);
  int pos = offsets[s] + atomicAdd(&cnt[s], 1);
  dst_s[pos] = d;
  ex_s[pos] = ex;
}

// ------- gather: one 64-lane wave per head node, bf16 messages ------------
__global__ __launch_bounds__(256) void gather_kernel(
    const ushort* __restrict__ rtail, const int* __restrict__ offsets,
    const int* __restrict__ dst_s, const float* __restrict__ ex_s,
    float* __restrict__ agg, int N) {
  int lane = threadIdx.x & 63;
  int node = blockIdx.x * 4 + (threadIdx.x >> 6);
  if (node >= N) return;
  int j0 = offsets[node], j1 = offsets[node + 1];

  float dsum = 0.f;
  for (int j = j0 + lane; j < j1; j += 64) dsum += ex_s[j];
#pragma unroll
  for (int m = 32; m >= 1; m >>= 1) dsum += __shfl_xor(dsum, m, 64);
  float inv = 1.f / (dsum + 1e-16f);

  float ax = 0.f, ay = 0.f;
  for (int j = j0; j < j1; ++j) {
    int d = dst_s[j];                      // wave-uniform broadcast
    float w = ex_s[j] * inv;
    unsigned v = *(const unsigned*)(rtail + (size_t)d * 128 + lane * 2);
    ax += b2f_lo(v) * w;
    ay += b2f_hi(v) * w;
  }
  float2 o = make_float2(ax, ay);
  *(float2*)(agg + (size_t)node * 128 + lane * 2) = o;
}

// ------------- relation combine: softmax over R relations, ReLU ------------
template <int R>
__global__ __launch_bounds__(256) void combine_kernel(
    const float* __restrict__ rel0, const float* __restrict__ rel1,
    const ushort* __restrict__ selfb, const float* __restrict__ convW,
    const float* __restrict__ convb, float* __restrict__ out, int N) {
  int lane = threadIdx.x & 63;
  int node = blockIdx.x * 4 + (threadIdx.x >> 6);
  if (node >= N) return;
  int c = lane * 2;
  const float w0 = convW[c], w1 = convW[c + 1];

  float2 v[R];
  v[0] = *(const float2*)(rel0 + (size_t)node * 128 + c);
  if constexpr (R == 3) v[1] = *(const float2*)(rel1 + (size_t)node * 128 + c);
  {
    unsigned sv = *(const unsigned*)(selfb + (size_t)node * 128 + c);
    v[R - 1] = make_float2(b2f_lo(sv), b2f_hi(sv));
  }
  float s[R];
#pragma unroll
  for (int r = 0; r < R; ++r) {
    float p = v[r].x * w0 + v[r].y * w1;
#pragma unroll
    for (int m = 32; m >= 1; m >>= 1) p += __shfl_xor(p, m, 64);
    s[r] = p + convb[0];
  }
  float mx = s[0];
#pragma unroll
  for (int r = 1; r < R; ++r) mx = fmaxf(mx, s[r]);
  float es[R], sum = 0.f;
#pragma unroll
  for (int r = 0; r < R; ++r) { es[r] = expf(s[r] - mx); sum += es[r]; }
  float ox = 0.f, oy = 0.f;
#pragma unroll
  for (int r = 0; r < R; ++r) {
    float b = es[r] / sum;
    ox += v[r].x * b;
    oy += v[r].y * b;
  }
  *(float2*)(out + (size_t)node * 128 + c) =
      make_float2(fmaxf(ox, 0.f), fmaxf(oy, 0.f));
}

// ---------------------------------------------------------------------------
extern "C" void kernel_launch(void* const* d_in, const int* in_sizes, int n_in,
                              void* d_out, int out_size, void* d_ws,
                              size_t ws_size, hipStream_t stream) {
  const float* x_gene  = (const float*)d_in[0];
  const float* x_prot  = (const float*)d_in[1];
  const float* Wl_gene = (const float*)d_in[2];
  const float* bl_gene = (const float*)d_in[3];
  const float* Wr_gene = (const float*)d_in[4];
  const float* br_gene = (const float*)d_in[5];
  const float* Wl_prot = (const float*)d_in[6];
  const float* bl_prot = (const float*)d_in[7];
  const float* Wr_prot = (const float*)d_in[8];
  const float* br_prot = (const float*)d_in[9];
  const float* alW     = (const float*)d_in[10];  // [3,32,128] contiguous
  const float* alb     = (const float*)d_in[11];  // [3,32] contiguous
  const float* arW     = (const float*)d_in[12];
  const float* arb     = (const float*)d_in[13];
  const float* qw      = (const float*)d_in[14];  // [3,64,1]
  const float* sharp   = (const float*)d_in[15];
  const float* cgW     = (const float*)d_in[16];
  const float* cgb     = (const float*)d_in[17];
  const float* cpW     = (const float*)d_in[18];
  const float* cpb     = (const float*)d_in[19];
  const int* e_gg      = (const int*)d_in[20];
  const int* e_gp      = (const int*)d_in[21];
  const int* e_pp      = (const int*)d_in[22];

  const int NG = in_sizes[0] / 256;
  const int NP = in_sizes[1] / 256;
  const int E  = in_sizes[20] / 2;
  const int NPG = (NG + 127) & ~127;   // padded rows
  const int NPP = (NP + 127) & ~127;
  const int M = (NG > NP) ? NG : NP;

  // ---- workspace layout (bytes), region0 aliased: xb -> attn outputs ----
  char* base = (char*)d_ws;
  size_t off = 0;
  auto alloc = [&](size_t bytes) {
    void* p = base + off;
    off = (off + bytes + 255) & ~(size_t)255;
    return p;
  };
  ushort* xb_gene = (ushort*)alloc((size_t)NPG * 256 * 2);
  ushort* xb_prot = (ushort*)alloc((size_t)NPP * 256 * 2);
  // aliases over xb region (valid after proj phase; 96*4=384 < 512 B/row)
  float* al_gene = (float*)xb_gene;                 // [NPG,64] = al0|al1
  float* ar_gene = al_gene + (size_t)NPG * 64;      // [NPG,32]
  float* al_prot = ar_gene + (size_t)NPG * 32;      // [NPP,32]
  float* ar_prot = al_prot + (size_t)NPP * 32;      // [NPP,64] = ar1|ar2

  ushort* Wlr_gene = (ushort*)alloc(256 * 256 * 2);
  ushort* Wlr_prot = (ushort*)alloc(256 * 256 * 2);
  ushort* alWb     = (ushort*)alloc(96 * 128 * 2);
  ushort* arWb     = (ushort*)alloc(96 * 128 * 2);
  ushort* lb_gene  = (ushort*)alloc((size_t)NPG * 128 * 2);
  ushort* rb_gene  = (ushort*)alloc((size_t)NPG * 128 * 2);
  ushort* lb_prot  = (ushort*)alloc((size_t)NPP * 128 * 2);
  ushort* rb_prot  = (ushort*)alloc((size_t)NPP * 128 * 2);
  float*  agg_gp   = (float*)alloc((size_t)NG * 128 * 4);
  // deg and cnt share ONE allocation so a single memset covers both exactly
  // (R3 bug: separate 256-aligned allocs left a poisoned gap in cnt).
  int*    deg      = (int*)alloc(2 * (size_t)M * 4);
  int*    cnt      = deg + M;
  int*    offsets  = (int*)alloc((size_t)(M + 1) * 4);
  int*    dst_s    = (int*)alloc((size_t)E * 4);
  float*  ex_s     = (float*)alloc((size_t)E * 4);

  float* out_gene = (float*)d_out;
  float* out_prot = out_gene + (size_t)NG * 128;

  dim3 blk(256);
  auto cvt_grid = [](int total) { return (total / 4 + 255) / 256; };

  // ---- 0) bf16 conversions ----
  cvt_bf16_kernel<<<cvt_grid(NPG * 256), blk, 0, stream>>>(x_gene, xb_gene, NG * 256, NPG * 256);
  cvt_bf16_kernel<<<cvt_grid(NPP * 256), blk, 0, stream>>>(x_prot, xb_prot, NP * 256, NPP * 256);
  cvt_bf16_kernel<<<cvt_grid(128 * 256), blk, 0, stream>>>(Wl_gene, Wlr_gene, 128 * 256, 128 * 256);
  cvt_bf16_kernel<<<cvt_grid(128 * 256), blk, 0, stream>>>(Wr_gene, Wlr_gene + 128 * 256, 128 * 256, 128 * 256);
  cvt_bf16_kernel<<<cvt_grid(128 * 256), blk, 0, stream>>>(Wl_prot, Wlr_prot, 128 * 256, 128 * 256);
  cvt_bf16_kernel<<<cvt_grid(128 * 256), blk, 0, stream>>>(Wr_prot, Wlr_prot + 128 * 256, 128 * 256, 128 * 256);
  cvt_bf16_kernel<<<cvt_grid(96 * 128), blk, 0, stream>>>(alW, alWb, 96 * 128, 96 * 128);
  cvt_bf16_kernel<<<cvt_grid(96 * 128), blk, 0, stream>>>(arW, arWb, 96 * 128, 96 * 128);

  // ---- 1) fused l/r projections (MFMA) ----
  proj_lr_mfma<<<dim3(NPG / 128, 2), blk, 0, stream>>>(xb_gene, Wlr_gene, bl_gene, br_gene, lb_gene, rb_gene, NG);
  proj_lr_mfma<<<dim3(NPP / 128, 2), blk, 0, stream>>>(xb_prot, Wlr_prot, bl_prot, br_prot, lb_prot, rb_prot, NP);

  // ---- 2) attention projections (MFMA); outputs overlay dead xb region ----
  attn_proj_mfma<64><<<NPG / 128, blk, 0, stream>>>(lb_gene, alWb, alb, al_gene, NG);                  // al0|al1
  attn_proj_mfma<32><<<NPG / 128, blk, 0, stream>>>(rb_gene, arWb, arb, ar_gene, NG);                  // ar0
  attn_proj_mfma<32><<<NPP / 128, blk, 0, stream>>>(lb_prot, alWb + 64 * 128, alb + 64, al_prot, NP);  // al2
  attn_proj_mfma<64><<<NPP / 128, blk, 0, stream>>>(rb_prot, arWb + 32 * 128, arb + 32, ar_prot, NP);  // ar1|ar2

  const int gridE = (E + 255) / 256;
  const int gridNG = (NG + 3) / 4;
  const int gridNP = (NP + 3) / 4;

  // ---- mp0: gene <- gene ----
  hipMemsetAsync(deg, 0, 2 * (size_t)M * sizeof(int), stream);
  hist_kernel<<<gridE, blk, 0, stream>>>(e_gg, deg, E);
  scan_kernel<<<1, 1024, 0, stream>>>(deg, offsets, NG);
  edge_logits_scatter<<<gridE, blk, 0, stream>>>(al_gene, 64, ar_gene, 32, e_gg, e_gg + E,
                                                 qw + 0 * 64, sharp + 0, offsets, cnt, dst_s, ex_s, E);
  gather_kernel<<<gridNG, blk, 0, stream>>>(rb_gene, offsets, dst_s, ex_s, out_gene, NG);

  // ---- mp1: gene <- protein ----
  hipMemsetAsync(deg, 0, 2 * (size_t)M * sizeof(int), stream);
  hist_kernel<<<gridE, blk, 0, stream>>>(e_gp, deg, E);
  scan_kernel<<<1, 1024, 0, stream>>>(deg, offsets, NG);
  edge_logits_scatter<<<gridE, blk, 0, stream>>>(al_gene + 32, 64, ar_prot, 64, e_gp, e_gp + E,
                                                 qw + 1 * 64, sharp + 1, offsets, cnt, dst_s, ex_s, E);
  gather_kernel<<<gridNG, blk, 0, stream>>>(rb_prot, offsets, dst_s, ex_s, agg_gp, NG);

  // ---- mp2: protein <- protein ----
  hipMemsetAsync(deg, 0, 2 * (size_t)M * sizeof(int), stream);
  hist_kernel<<<gridE, blk, 0, stream>>>(e_pp, deg, E);
  scan_kernel<<<1, 1024, 0, stream>>>(deg, offsets, NP);
  edge_logits_scatter<<<gridE, blk, 0, stream>>>(al_prot, 32, ar_prot + 32, 64, e_pp, e_pp + E,
                                                 qw + 2 * 64, sharp + 2, offsets, cnt, dst_s, ex_s, E);
  gather_kernel<<<gridNP, blk, 0, stream>>>(rb_prot, offsets, dst_s, ex_s, out_prot, NP);

  // ---- combine ----
  combine_kernel<3><<<gridNG, blk, 0, stream>>>(out_gene, agg_gp, lb_gene, cgW, cgb, out_gene, NG);
  combine_kernel<2><<<gridNP, blk, 0, stream>>>(out_prot, nullptr, lb_prot, cpW, cpb, out_prot, NP);
}

// Round 5
// 846.070 us; speedup vs baseline: 4.0178x; 1.0554x over previous
//
#include <hip/hip_runtime.h>
#include <hip/hip_bf16.h>

// ---------------------------------------------------------------------------
// LATTE heterogeneous GNN layer (gene/protein).
// R5: tanh([a_i,a_j]).qw split algebraically into per-node scalars
//     tl[s] + tr[d]  (tanh is elementwise, dot is linear -> exact).
//     Edge stage now gathers 2x4B from 200KB tables instead of 2x128B from
//     19MB tables, and does zero tanh. CSR record packed to one uint2 store.
//     Parallel 2-pass scan. Gather uses chunked record loads + shuffle bcast.
// ---------------------------------------------------------------------------

typedef __attribute__((ext_vector_type(8))) short short8;   // 8 bf16
typedef __attribute__((ext_vector_type(4))) float floatx4;  // 4 f32 acc

__device__ __forceinline__ void gload16(const void* g, void* l) {
  __builtin_amdgcn_global_load_lds(
      (const __attribute__((address_space(1))) void*)g,
      (__attribute__((address_space(3))) void*)l, 16, 0, 0);
}

__device__ __forceinline__ ushort f2b(float x) {
  __hip_bfloat16 h = __float2bfloat16(x);
  return *reinterpret_cast<ushort*>(&h);
}
__device__ __forceinline__ float b2f_lo(unsigned v) { return __uint_as_float(v << 16); }
__device__ __forceinline__ float b2f_hi(unsigned v) { return __uint_as_float(v & 0xffff0000u); }

// ---------------- fp32 -> bf16 convert (with zero row padding) -------------
__global__ __launch_bounds__(256) void cvt_bf16_kernel(
    const float* __restrict__ src, ushort* __restrict__ dst, int valid, int total) {
  int i = (blockIdx.x * 256 + threadIdx.x) * 4;
  if (i >= total) return;
  float4 v = make_float4(0.f, 0.f, 0.f, 0.f);
  if (i < valid) v = *(const float4*)(src + i);
  ushort4 o;
  o.x = f2b(v.x); o.y = f2b(v.y); o.z = f2b(v.z); o.w = f2b(v.w);
  *(ushort4*)(dst + i) = o;
}

// ------------- fused l/r projection: [NPAD,256]bf16 @ [256,256]^T ----------
__global__ __launch_bounds__(256) void proj_lr_mfma(
    const ushort* __restrict__ xb, const ushort* __restrict__ Wb,
    const float* __restrict__ bl, const float* __restrict__ br,
    ushort* __restrict__ lb, ushort* __restrict__ rb, int N) {
  __shared__ ushort As[128 * 32];
  __shared__ ushort Bs[128 * 32];
  const int tid = threadIdx.x;
  const int lane = tid & 63;
  const int wave = tid >> 6;
  const int wm = wave & 1, wn = wave >> 1;
  const int rowBase = blockIdx.x * 128;
  const int colHalf = blockIdx.y;
  const ushort* Wbase = Wb + (size_t)colHalf * 128 * 256;

  floatx4 acc[4][4] = {};

  const int srow = tid >> 2, schk = tid & 3;
  for (int k0 = 0; k0 < 256; k0 += 32) {
#pragma unroll
    for (int i = 0; i < 2; ++i) {
      gload16(xb + (size_t)(rowBase + srow + i * 64) * 256 + k0 + schk * 8,
              &As[(tid + i * 256) * 8]);
      gload16(Wbase + (size_t)(srow + i * 64) * 256 + k0 + schk * 8,
              &Bs[(tid + i * 256) * 8]);
    }
    __syncthreads();
    short8 bf[4];
#pragma unroll
    for (int nt = 0; nt < 4; ++nt)
      bf[nt] = *(const short8*)&Bs[(wn * 64 + nt * 16 + (lane & 15)) * 32 + (lane >> 4) * 8];
#pragma unroll
    for (int mt = 0; mt < 4; ++mt) {
      short8 a = *(const short8*)&As[(wm * 64 + mt * 16 + (lane & 15)) * 32 + (lane >> 4) * 8];
#pragma unroll
      for (int nt = 0; nt < 4; ++nt)
        acc[mt][nt] = __builtin_amdgcn_mfma_f32_16x16x32_bf16(a, bf[nt], acc[mt][nt], 0, 0, 0);
    }
    __syncthreads();
  }

  const float* bias = colHalf ? br : bl;
  ushort* outp = colHalf ? rb : lb;
#pragma unroll
  for (int mt = 0; mt < 4; ++mt)
#pragma unroll
    for (int nt = 0; nt < 4; ++nt) {
      int col = wn * 64 + nt * 16 + (lane & 15);
      float bv = bias[col];
#pragma unroll
      for (int vi = 0; vi < 4; ++vi) {
        int row = rowBase + wm * 64 + mt * 16 + (lane >> 4) * 4 + vi;
        if (row < N) outp[(size_t)row * 128 + col] = f2b(acc[mt][nt][vi] + bv);
      }
    }
}

// ------------- attention projection: [NPAD,128]bf16 @ [BN,128]^T -> f32 ----
template <int BN>
__global__ __launch_bounds__(256) void attn_proj_mfma(
    const ushort* __restrict__ Ab, const ushort* __restrict__ Wb,
    const float* __restrict__ bias, float* __restrict__ out, int N) {
  __shared__ ushort As[128 * 32];
  __shared__ ushort Ws[BN * 128];
  const int tid = threadIdx.x;
  const int lane = tid & 63;
  const int wave = tid >> 6;
  const int rowBase = blockIdx.x * 128;

#pragma unroll
  for (int i = 0; i < (BN * 16) / 256; ++i) {
    int idx = tid + i * 256;
    gload16(Wb + (size_t)idx * 8, &Ws[idx * 8]);
  }

  floatx4 acc[2][BN / 16] = {};
  for (int k0 = 0; k0 < 128; k0 += 32) {
#pragma unroll
    for (int i = 0; i < 2; ++i) {
      int t = tid + i * 256;
      gload16(Ab + (size_t)(rowBase + (t >> 2)) * 128 + k0 + (t & 3) * 8, &As[t * 8]);
    }
    __syncthreads();
    short8 bf[BN / 16];
#pragma unroll
    for (int nt = 0; nt < BN / 16; ++nt)
      bf[nt] = *(const short8*)&Ws[(nt * 16 + (lane & 15)) * 128 + k0 + (lane >> 4) * 8];
#pragma unroll
    for (int mt = 0; mt < 2; ++mt) {
      short8 a = *(const short8*)&As[(wave * 32 + mt * 16 + (lane & 15)) * 32 + (lane >> 4) * 8];
#pragma unroll
      for (int nt = 0; nt < BN / 16; ++nt)
        acc[mt][nt] = __builtin_amdgcn_mfma_f32_16x16x32_bf16(a, bf[nt], acc[mt][nt], 0, 0, 0);
    }
    __syncthreads();
  }
#pragma unroll
  for (int mt = 0; mt < 2; ++mt)
#pragma unroll
    for (int nt = 0; nt < BN / 16; ++nt) {
      int col = nt * 16 + (lane & 15);
      float bv = bias[col];
#pragma unroll
      for (int vi = 0; vi < 4; ++vi) {
        int row = rowBase + wave * 32 + mt * 16 + (lane >> 4) * 4 + vi;
        if (row < N) out[(size_t)row * BN + col] = acc[mt][nt][vi] + bv;
      }
    }
}

// ------- per-node tanh-dot: out[n] = sum_c tanh(a[n][c]) * q[c], c<32 ------
__global__ __launch_bounds__(256) void tanh_dot_kernel(
    const float* __restrict__ a, int stride, const float* __restrict__ q,
    float* __restrict__ out, int N) {
  int lane32 = threadIdx.x & 31;
  int node = blockIdx.x * 8 + (threadIdx.x >> 5);
  if (node >= N) return;
  float p = tanhf(a[(size_t)node * stride + lane32]) * q[lane32];
#pragma unroll
  for (int m = 16; m >= 1; m >>= 1) p += __shfl_xor(p, m, 32);
  if (lane32 == 0) out[node] = p;
}

// ---------------- degree histogram ----------------------------------------
__global__ __launch_bounds__(256) void hist_kernel(
    const int* __restrict__ src, int* __restrict__ deg, int E) {
  int e = blockIdx.x * 256 + threadIdx.x;
  if (e < E) atomicAdd(&deg[src[e]], 1);
}

// ------- single-block 2-pass prefix sum: serial chunk + block scan --------
__global__ __launch_bounds__(1024) void scan_kernel(
    const int* __restrict__ deg, int* __restrict__ offsets, int n) {
  __shared__ int wsum[16];
  const int t = threadIdx.x;
  const int C = (n + 1023) / 1024;
  const int begin = t * C;
  const int end = min(begin + C, n);

  int s = 0;
  for (int i = begin; i < end; ++i) s += deg[i];

  const int lane = t & 63, wv = t >> 6;
  int x = s;
#pragma unroll
  for (int off = 1; off < 64; off <<= 1) {
    int u = __shfl_up(x, off, 64);
    if (lane >= off) x += u;
  }
  if (lane == 63) wsum[wv] = x;
  __syncthreads();
  int wpre = 0;
#pragma unroll
  for (int j = 0; j < 16; ++j) wpre += (j < wv) ? wsum[j] : 0;
  int run = wpre + x - s;  // exclusive prefix of this thread's chunk

  for (int i = begin; i < end; ++i) {
    offsets[i] = run;
    run += deg[i];
  }
  if (end == n) offsets[n] = run;  // several threads may write; same value
}

// ------- edge logits + sorted scatter of packed (dst, ex) records ---------
__global__ __launch_bounds__(256) void edge_logits_scatter(
    const float* __restrict__ tl, const float* __restrict__ tr,
    const int* __restrict__ src, const int* __restrict__ dst,
    const float* __restrict__ sharp_mp, const int* __restrict__ offsets,
    int* __restrict__ cnt, uint2* __restrict__ rec, int E) {
  int e = blockIdx.x * 256 + threadIdx.x;
  if (e >= E) return;
  int s = src[e], d = dst[e];
  // |tl+tr| <= sum|qw| ~ 10 -> exp safe in fp32 without max-shift.
  float ex = expf((tl[s] + tr[d]) * sharp_mp[0]);
  int pos = offsets[s] + atomicAdd(&cnt[s], 1);
  rec[pos] = make_uint2((unsigned)d, __float_as_uint(ex));
}

// ------- gather: wave per head node, chunked records + shuffle bcast ------
__global__ __launch_bounds__(256) void gather_kernel(
    const ushort* __restrict__ rtail, const int* __restrict__ offsets,
    const uint2* __restrict__ rec, float* __restrict__ agg, int N) {
  int lane = threadIdx.x & 63;
  int node = blockIdx.x * 4 + (threadIdx.x >> 6);
  if (node >= N) return;
  int j0 = offsets[node], j1 = offsets[node + 1];

  float ax = 0.f, ay = 0.f, dsum = 0.f;
  for (int base = j0; base < j1; base += 64) {
    int cntc = min(64, j1 - base);
    uint2 my = make_uint2(0u, 0u);
    if (lane < cntc) {
      my = rec[base + lane];
      dsum += __uint_as_float(my.y);
    }
    for (int k = 0; k < cntc; ++k) {
      int d = __shfl((int)my.x, k, 64);
      float w = __shfl(__uint_as_float(my.y), k, 64);
      unsigned v = *(const unsigned*)(rtail + (size_t)d * 128 + lane * 2);
      ax += b2f_lo(v) * w;
      ay += b2f_hi(v) * w;
    }
  }
#pragma unroll
  for (int m = 32; m >= 1; m >>= 1) dsum += __shfl_xor(dsum, m, 64);
  float inv = 1.f / (dsum + 1e-16f);
  *(float2*)(agg + (size_t)node * 128 + lane * 2) = make_float2(ax * inv, ay * inv);
}

// ------------- relation combine: softmax over R relations, ReLU ------------
template <int R>
__global__ __launch_bounds__(256) void combine_kernel(
    const float* __restrict__ rel0, const float* __restrict__ rel1,
    const ushort* __restrict__ selfb, const float* __restrict__ convW,
    const float* __restrict__ convb, float* __restrict__ out, int N) {
  int lane = threadIdx.x & 63;
  int node = blockIdx.x * 4 + (threadIdx.x >> 6);
  if (node >= N) return;
  int c = lane * 2;
  const float w0 = convW[c], w1 = convW[c + 1];

  float2 v[R];
  v[0] = *(const float2*)(rel0 + (size_t)node * 128 + c);
  if constexpr (R == 3) v[1] = *(const float2*)(rel1 + (size_t)node * 128 + c);
  {
    unsigned sv = *(const unsigned*)(selfb + (size_t)node * 128 + c);
    v[R - 1] = make_float2(b2f_lo(sv), b2f_hi(sv));
  }
  float s[R];
#pragma unroll
  for (int r = 0; r < R; ++r) {
    float p = v[r].x * w0 + v[r].y * w1;
#pragma unroll
    for (int m = 32; m >= 1; m >>= 1) p += __shfl_xor(p, m, 64);
    s[r] = p + convb[0];
  }
  float mx = s[0];
#pragma unroll
  for (int r = 1; r < R; ++r) mx = fmaxf(mx, s[r]);
  float es[R], sum = 0.f;
#pragma unroll
  for (int r = 0; r < R; ++r) { es[r] = expf(s[r] - mx); sum += es[r]; }
  float ox = 0.f, oy = 0.f;
#pragma unroll
  for (int r = 0; r < R; ++r) {
    float b = es[r] / sum;
    ox += v[r].x * b;
    oy += v[r].y * b;
  }
  *(float2*)(out + (size_t)node * 128 + c) =
      make_float2(fmaxf(ox, 0.f), fmaxf(oy, 0.f));
}

// ---------------------------------------------------------------------------
extern "C" void kernel_launch(void* const* d_in, const int* in_sizes, int n_in,
                              void* d_out, int out_size, void* d_ws,
                              size_t ws_size, hipStream_t stream) {
  const float* x_gene  = (const float*)d_in[0];
  const float* x_prot  = (const float*)d_in[1];
  const float* Wl_gene = (const float*)d_in[2];
  const float* bl_gene = (const float*)d_in[3];
  const float* Wr_gene = (const float*)d_in[4];
  const float* br_gene = (const float*)d_in[5];
  const float* Wl_prot = (const float*)d_in[6];
  const float* bl_prot = (const float*)d_in[7];
  const float* Wr_prot = (const float*)d_in[8];
  const float* br_prot = (const float*)d_in[9];
  const float* alW     = (const float*)d_in[10];  // [3,32,128] contiguous
  const float* alb     = (const float*)d_in[11];  // [3,32] contiguous
  const float* arW     = (const float*)d_in[12];
  const float* arb     = (const float*)d_in[13];
  const float* qw      = (const float*)d_in[14];  // [3,64,1]
  const float* sharp   = (const float*)d_in[15];
  const float* cgW     = (const float*)d_in[16];
  const float* cgb     = (const float*)d_in[17];
  const float* cpW     = (const float*)d_in[18];
  const float* cpb     = (const float*)d_in[19];
  const int* e_gg      = (const int*)d_in[20];
  const int* e_gp      = (const int*)d_in[21];
  const int* e_pp      = (const int*)d_in[22];

  const int NG = in_sizes[0] / 256;
  const int NP = in_sizes[1] / 256;
  const int E  = in_sizes[20] / 2;
  const int NPG = (NG + 127) & ~127;
  const int NPP = (NP + 127) & ~127;
  const int M = (NG > NP) ? NG : NP;

  char* base = (char*)d_ws;
  size_t off = 0;
  auto alloc = [&](size_t bytes) {
    void* p = base + off;
    off = (off + bytes + 255) & ~(size_t)255;
    return p;
  };
  ushort* xb_gene = (ushort*)alloc((size_t)NPG * 256 * 2);
  ushort* xb_prot = (ushort*)alloc((size_t)NPP * 256 * 2);
  // aliases over xb region (valid after proj phase; 96*4=384 < 512 B/row)
  float* al_gene = (float*)xb_gene;                 // [NPG,64] = al0|al1
  float* ar_gene = al_gene + (size_t)NPG * 64;      // [NPG,32]
  float* al_prot = ar_gene + (size_t)NPG * 32;      // [NPP,32]
  float* ar_prot = al_prot + (size_t)NPP * 32;      // [NPP,64] = ar1|ar2

  ushort* Wlr_gene = (ushort*)alloc(256 * 256 * 2);
  ushort* Wlr_prot = (ushort*)alloc(256 * 256 * 2);
  ushort* alWb     = (ushort*)alloc(96 * 128 * 2);
  ushort* arWb     = (ushort*)alloc(96 * 128 * 2);
  ushort* lb_gene  = (ushort*)alloc((size_t)NPG * 128 * 2);
  ushort* rb_gene  = (ushort*)alloc((size_t)NPG * 128 * 2);
  ushort* lb_prot  = (ushort*)alloc((size_t)NPP * 128 * 2);
  ushort* rb_prot  = (ushort*)alloc((size_t)NPP * 128 * 2);
  float*  agg_gp   = (float*)alloc((size_t)NG * 128 * 4);
  int*    deg      = (int*)alloc(2 * (size_t)M * 4);  // deg+cnt: one memset
  int*    cnt      = deg + M;
  int*    offsets  = (int*)alloc((size_t)(M + 1) * 4);
  uint2*  rec      = (uint2*)alloc((size_t)E * 8);
  float*  tlt      = (float*)alloc(6 * (size_t)M * 4);
  float* tl_gg = tlt,         * tr_gg = tlt + M;
  float* tl_gp = tlt + 2 * M, * tr_gp = tlt + 3 * M;
  float* tl_pp = tlt + 4 * M, * tr_pp = tlt + 5 * M;

  float* out_gene = (float*)d_out;
  float* out_prot = out_gene + (size_t)NG * 128;

  dim3 blk(256);
  auto cvt_grid = [](int total) { return (total / 4 + 255) / 256; };

  // ---- 0) bf16 conversions ----
  cvt_bf16_kernel<<<cvt_grid(NPG * 256), blk, 0, stream>>>(x_gene, xb_gene, NG * 256, NPG * 256);
  cvt_bf16_kernel<<<cvt_grid(NPP * 256), blk, 0, stream>>>(x_prot, xb_prot, NP * 256, NPP * 256);
  cvt_bf16_kernel<<<cvt_grid(128 * 256), blk, 0, stream>>>(Wl_gene, Wlr_gene, 128 * 256, 128 * 256);
  cvt_bf16_kernel<<<cvt_grid(128 * 256), blk, 0, stream>>>(Wr_gene, Wlr_gene + 128 * 256, 128 * 256, 128 * 256);
  cvt_bf16_kernel<<<cvt_grid(128 * 256), blk, 0, stream>>>(Wl_prot, Wlr_prot, 128 * 256, 128 * 256);
  cvt_bf16_kernel<<<cvt_grid(128 * 256), blk, 0, stream>>>(Wr_prot, Wlr_prot + 128 * 256, 128 * 256, 128 * 256);
  cvt_bf16_kernel<<<cvt_grid(96 * 128), blk, 0, stream>>>(alW, alWb, 96 * 128, 96 * 128);
  cvt_bf16_kernel<<<cvt_grid(96 * 128), blk, 0, stream>>>(arW, arWb, 96 * 128, 96 * 128);

  // ---- 1) fused l/r projections (MFMA) ----
  proj_lr_mfma<<<dim3(NPG / 128, 2), blk, 0, stream>>>(xb_gene, Wlr_gene, bl_gene, br_gene, lb_gene, rb_gene, NG);
  proj_lr_mfma<<<dim3(NPP / 128, 2), blk, 0, stream>>>(xb_prot, Wlr_prot, bl_prot, br_prot, lb_prot, rb_prot, NP);

  // ---- 2) attention projections (MFMA); outputs overlay dead xb region ----
  attn_proj_mfma<64><<<NPG / 128, blk, 0, stream>>>(lb_gene, alWb, alb, al_gene, NG);                  // al0|al1
  attn_proj_mfma<32><<<NPG / 128, blk, 0, stream>>>(rb_gene, arWb, arb, ar_gene, NG);                  // ar0
  attn_proj_mfma<32><<<NPP / 128, blk, 0, stream>>>(lb_prot, alWb + 64 * 128, alb + 64, al_prot, NP);  // al2
  attn_proj_mfma<64><<<NPP / 128, blk, 0, stream>>>(rb_prot, arWb + 32 * 128, arb + 32, ar_prot, NP);  // ar1|ar2

  // ---- 3) per-node tanh-dot scalars (exact split of the edge logit) ----
  const int gridTG = (NG + 7) / 8, gridTP = (NP + 7) / 8;
  tanh_dot_kernel<<<gridTG, blk, 0, stream>>>(al_gene,      64, qw + 0,        tl_gg, NG);
  tanh_dot_kernel<<<gridTG, blk, 0, stream>>>(ar_gene,      32, qw + 32,       tr_gg, NG);
  tanh_dot_kernel<<<gridTG, blk, 0, stream>>>(al_gene + 32, 64, qw + 64,       tl_gp, NG);
  tanh_dot_kernel<<<gridTP, blk, 0, stream>>>(ar_prot,      64, qw + 64 + 32,  tr_gp, NP);
  tanh_dot_kernel<<<gridTP, blk, 0, stream>>>(al_prot,      32, qw + 128,      tl_pp, NP);
  tanh_dot_kernel<<<gridTP, blk, 0, stream>>>(ar_prot + 32, 64, qw + 128 + 32, tr_pp, NP);

  const int gridE = (E + 255) / 256;
  const int gridNG = (NG + 3) / 4;
  const int gridNP = (NP + 3) / 4;

  // ---- mp0: gene <- gene ----
  hipMemsetAsync(deg, 0, 2 * (size_t)M * sizeof(int), stream);
  hist_kernel<<<gridE, blk, 0, stream>>>(e_gg, deg, E);
  scan_kernel<<<1, 1024, 0, stream>>>(deg, offsets, NG);
  edge_logits_scatter<<<gridE, blk, 0, stream>>>(tl_gg, tr_gg, e_gg, e_gg + E, sharp + 0,
                                                 offsets, cnt, rec, E);
  gather_kernel<<<gridNG, blk, 0, stream>>>(rb_gene, offsets, rec, out_gene, NG);

  // ---- mp1: gene <- protein ----
  hipMemsetAsync(deg, 0, 2 * (size_t)M * sizeof(int), stream);
  hist_kernel<<<gridE, blk, 0, stream>>>(e_gp, deg, E);
  scan_kernel<<<1, 1024, 0, stream>>>(deg, offsets, NG);
  edge_logits_scatter<<<gridE, blk, 0, stream>>>(tl_gp, tr_gp, e_gp, e_gp + E, sharp + 1,
                                                 offsets, cnt, rec, E);
  gather_kernel<<<gridNG, blk, 0, stream>>>(rb_prot, offsets, rec, agg_gp, NG);

  // ---- mp2: protein <- protein ----
  hipMemsetAsync(deg, 0, 2 * (size_t)M * sizeof(int), stream);
  hist_kernel<<<gridE, blk, 0, stream>>>(e_pp, deg, E);
  scan_kernel<<<1, 1024, 0, stream>>>(deg, offsets, NP);
  edge_logits_scatter<<<gridE, blk, 0, stream>>>(tl_pp, tr_pp, e_pp, e_pp + E, sharp + 2,
                                                 offsets, cnt, rec, E);
  gather_kernel<<<gridNP, blk, 0, stream>>>(rb_prot, offsets, rec, out_prot, NP);

  // ---- combine ----
  combine_kernel<3><<<gridNG, blk, 0, stream>>>(out_gene, agg_gp, lb_gene, cgW, cgb, out_gene, NG);
  combine_kernel<2><<<gridNP, blk, 0, stream>>>(out_prot, nullptr, lb_prot, cpW, cpb, out_prot, NP);
}

// Round 6
// 603.185 us; speedup vs baseline: 5.6356x; 1.4027x over previous
//
#include <hip/hip_runtime.h>
#include <hip/hip_bf16.h>

// ---------------------------------------------------------------------------
// LATTE heterogeneous GNN layer (gene/protein).
// R6: all 3 metapaths share ONE concatenated CSR (head-node space
//     [gene|gene|prot], NT=2NG+NP) -> single hist / scan / logits / gather.
//     Scan is hierarchical (tile-scan -> partials -> add), ~12 us total vs
//     R5's 229 us single-block straggler (0.14% occupancy on profile).
// ---------------------------------------------------------------------------

typedef __attribute__((ext_vector_type(8))) short short8;   // 8 bf16
typedef __attribute__((ext_vector_type(4))) float floatx4;  // 4 f32 acc

__device__ __forceinline__ void gload16(const void* g, void* l) {
  __builtin_amdgcn_global_load_lds(
      (const __attribute__((address_space(1))) void*)g,
      (__attribute__((address_space(3))) void*)l, 16, 0, 0);
}

__device__ __forceinline__ ushort f2b(float x) {
  __hip_bfloat16 h = __float2bfloat16(x);
  return *reinterpret_cast<ushort*>(&h);
}
__device__ __forceinline__ float b2f_lo(unsigned v) { return __uint_as_float(v << 16); }
__device__ __forceinline__ float b2f_hi(unsigned v) { return __uint_as_float(v & 0xffff0000u); }

// ---------------- fp32 -> bf16 convert (with zero row padding) -------------
__global__ __launch_bounds__(256) void cvt_bf16_kernel(
    const float* __restrict__ src, ushort* __restrict__ dst, int valid, int total) {
  int i = (blockIdx.x * 256 + threadIdx.x) * 4;
  if (i >= total) return;
  float4 v = make_float4(0.f, 0.f, 0.f, 0.f);
  if (i < valid) v = *(const float4*)(src + i);
  ushort4 o;
  o.x = f2b(v.x); o.y = f2b(v.y); o.z = f2b(v.z); o.w = f2b(v.w);
  *(ushort4*)(dst + i) = o;
}

// ------------- fused l/r projection: [NPAD,256]bf16 @ [256,256]^T ----------
__global__ __launch_bounds__(256) void proj_lr_mfma(
    const ushort* __restrict__ xb, const ushort* __restrict__ Wb,
    const float* __restrict__ bl, const float* __restrict__ br,
    ushort* __restrict__ lb, ushort* __restrict__ rb, int N) {
  __shared__ ushort As[128 * 32];
  __shared__ ushort Bs[128 * 32];
  const int tid = threadIdx.x;
  const int lane = tid & 63;
  const int wave = tid >> 6;
  const int wm = wave & 1, wn = wave >> 1;
  const int rowBase = blockIdx.x * 128;
  const int colHalf = blockIdx.y;
  const ushort* Wbase = Wb + (size_t)colHalf * 128 * 256;

  floatx4 acc[4][4] = {};

  const int srow = tid >> 2, schk = tid & 3;
  for (int k0 = 0; k0 < 256; k0 += 32) {
#pragma unroll
    for (int i = 0; i < 2; ++i) {
      gload16(xb + (size_t)(rowBase + srow + i * 64) * 256 + k0 + schk * 8,
              &As[(tid + i * 256) * 8]);
      gload16(Wbase + (size_t)(srow + i * 64) * 256 + k0 + schk * 8,
              &Bs[(tid + i * 256) * 8]);
    }
    __syncthreads();
    short8 bf[4];
#pragma unroll
    for (int nt = 0; nt < 4; ++nt)
      bf[nt] = *(const short8*)&Bs[(wn * 64 + nt * 16 + (lane & 15)) * 32 + (lane >> 4) * 8];
#pragma unroll
    for (int mt = 0; mt < 4; ++mt) {
      short8 a = *(const short8*)&As[(wm * 64 + mt * 16 + (lane & 15)) * 32 + (lane >> 4) * 8];
#pragma unroll
      for (int nt = 0; nt < 4; ++nt)
        acc[mt][nt] = __builtin_amdgcn_mfma_f32_16x16x32_bf16(a, bf[nt], acc[mt][nt], 0, 0, 0);
    }
    __syncthreads();
  }

  const float* bias = colHalf ? br : bl;
  ushort* outp = colHalf ? rb : lb;
#pragma unroll
  for (int mt = 0; mt < 4; ++mt)
#pragma unroll
    for (int nt = 0; nt < 4; ++nt) {
      int col = wn * 64 + nt * 16 + (lane & 15);
      float bv = bias[col];
#pragma unroll
      for (int vi = 0; vi < 4; ++vi) {
        int row = rowBase + wm * 64 + mt * 16 + (lane >> 4) * 4 + vi;
        if (row < N) outp[(size_t)row * 128 + col] = f2b(acc[mt][nt][vi] + bv);
      }
    }
}

// ------------- attention projection: [NPAD,128]bf16 @ [BN,128]^T -> f32 ----
template <int BN>
__global__ __launch_bounds__(256) void attn_proj_mfma(
    const ushort* __restrict__ Ab, const ushort* __restrict__ Wb,
    const float* __restrict__ bias, float* __restrict__ out, int N) {
  __shared__ ushort As[128 * 32];
  __shared__ ushort Ws[BN * 128];
  const int tid = threadIdx.x;
  const int lane = tid & 63;
  const int wave = tid >> 6;
  const int rowBase = blockIdx.x * 128;

#pragma unroll
  for (int i = 0; i < (BN * 16) / 256; ++i) {
    int idx = tid + i * 256;
    gload16(Wb + (size_t)idx * 8, &Ws[idx * 8]);
  }

  floatx4 acc[2][BN / 16] = {};
  for (int k0 = 0; k0 < 128; k0 += 32) {
#pragma unroll
    for (int i = 0; i < 2; ++i) {
      int t = tid + i * 256;
      gload16(Ab + (size_t)(rowBase + (t >> 2)) * 128 + k0 + (t & 3) * 8, &As[t * 8]);
    }
    __syncthreads();
    short8 bf[BN / 16];
#pragma unroll
    for (int nt = 0; nt < BN / 16; ++nt)
      bf[nt] = *(const short8*)&Ws[(nt * 16 + (lane & 15)) * 128 + k0 + (lane >> 4) * 8];
#pragma unroll
    for (int mt = 0; mt < 2; ++mt) {
      short8 a = *(const short8*)&As[(wave * 32 + mt * 16 + (lane & 15)) * 32 + (lane >> 4) * 8];
#pragma unroll
      for (int nt = 0; nt < BN / 16; ++nt)
        acc[mt][nt] = __builtin_amdgcn_mfma_f32_16x16x32_bf16(a, bf[nt], acc[mt][nt], 0, 0, 0);
    }
    __syncthreads();
  }
#pragma unroll
  for (int mt = 0; mt < 2; ++mt)
#pragma unroll
    for (int nt = 0; nt < BN / 16; ++nt) {
      int col = nt * 16 + (lane & 15);
      float bv = bias[col];
#pragma unroll
      for (int vi = 0; vi < 4; ++vi) {
        int row = rowBase + wave * 32 + mt * 16 + (lane >> 4) * 4 + vi;
        if (row < N) out[(size_t)row * BN + col] = acc[mt][nt][vi] + bv;
      }
    }
}

// ------- per-node tanh-dot: out[n] = sum_c tanh(a[n][c]) * q[c], c<32 ------
__global__ __launch_bounds__(256) void tanh_dot_kernel(
    const float* __restrict__ a, int stride, const float* __restrict__ q,
    float* __restrict__ out, int N) {
  int lane32 = threadIdx.x & 31;
  int node = blockIdx.x * 8 + (threadIdx.x >> 5);
  if (node >= N) return;
  float p = tanhf(a[(size_t)node * stride + lane32]) * q[lane32];
#pragma unroll
  for (int m = 16; m >= 1; m >>= 1) p += __shfl_xor(p, m, 32);
  if (lane32 == 0) out[node] = p;
}

// ------- hist over all 3 edge lists into concatenated head-node space -----
__global__ __launch_bounds__(256) void hist3_kernel(
    const int* __restrict__ e0, const int* __restrict__ e1,
    const int* __restrict__ e2, int* __restrict__ deg, int E, int NG) {
  int e = blockIdx.x * 256 + threadIdx.x;
  if (e >= 3 * E) return;
  int mp = (e >= 2 * E) ? 2 : ((e >= E) ? 1 : 0);
  int el = e - mp * E;
  const int* ep = (mp == 0) ? e0 : (mp == 1) ? e1 : e2;
  int segb = (mp == 2) ? 2 * NG : mp * NG;
  atomicAdd(&deg[segb + ep[el]], 1);
}

// ------- hierarchical scan: A) tile scan, B) partials, C) add prefix ------
// tile = 2048 elements (256 thr x 8)
__global__ __launch_bounds__(256) void scanA_kernel(
    const int* __restrict__ deg, int* __restrict__ offsets,
    int* __restrict__ tile_tot, int n) {
  __shared__ int wtot[4];
  const int t = threadIdx.x;
  const int base = blockIdx.x * 2048 + t * 8;
  int v[8], pre[8], s = 0;
#pragma unroll
  for (int j = 0; j < 8; ++j) {
    v[j] = (base + j < n) ? deg[base + j] : 0;
    pre[j] = s;
    s += v[j];
  }
  const int lane = t & 63, wv = t >> 6;
  int x = s;
#pragma unroll
  for (int o = 1; o < 64; o <<= 1) {
    int u = __shfl_up(x, o, 64);
    if (lane >= o) x += u;
  }
  if (lane == 63) wtot[wv] = x;
  __syncthreads();
  int wpre = 0;
#pragma unroll
  for (int j = 0; j < 4; ++j) wpre += (j < wv) ? wtot[j] : 0;
  int excl = wpre + x - s;
#pragma unroll
  for (int j = 0; j < 8; ++j)
    if (base + j < n) offsets[base + j] = excl + pre[j];
  if (t == 255) tile_tot[blockIdx.x] = wpre + x;
}

__global__ __launch_bounds__(256) void scanB_kernel(
    const int* __restrict__ tile_tot, int* __restrict__ tile_pre,
    int* __restrict__ offsets, int T, int n) {
  __shared__ int wtot[4];
  const int t = threadIdx.x;
  int v = (t < T) ? tile_tot[t] : 0;
  const int lane = t & 63, wv = t >> 6;
  int x = v;
#pragma unroll
  for (int o = 1; o < 64; o <<= 1) {
    int u = __shfl_up(x, o, 64);
    if (lane >= o) x += u;
  }
  if (lane == 63) wtot[wv] = x;
  __syncthreads();
  int wpre = 0;
#pragma unroll
  for (int j = 0; j < 4; ++j) wpre += (j < wv) ? wtot[j] : 0;
  if (t < T) tile_pre[t] = wpre + x - v;
  if (t == 255) offsets[n] = wpre + x;  // grand total
}

__global__ __launch_bounds__(256) void scanC_kernel(
    int* __restrict__ offsets, const int* __restrict__ tile_pre, int n) {
  const int add = tile_pre[blockIdx.x];
  const int base = blockIdx.x * 2048 + threadIdx.x * 8;
#pragma unroll
  for (int j = 0; j < 8; ++j)
    if (base + j < n) offsets[base + j] += add;
}

// ------- edge logits + sorted scatter over all 3 metapaths ----------------
__global__ __launch_bounds__(256) void edge_logits3(
    const float* __restrict__ tl3, const float* __restrict__ tr3,
    const int* __restrict__ e0, const int* __restrict__ e1,
    const int* __restrict__ e2, const float* __restrict__ sharp,
    const int* __restrict__ offsets, int* __restrict__ cnt,
    uint2* __restrict__ rec, int E, int NG, int NP) {
  int e = blockIdx.x * 256 + threadIdx.x;
  if (e >= 3 * E) return;
  int mp = (e >= 2 * E) ? 2 : ((e >= E) ? 1 : 0);
  int el = e - mp * E;
  const int* ep = (mp == 0) ? e0 : (mp == 1) ? e1 : e2;
  int s = ep[el], d = ep[el + E];
  int hb = (mp == 2) ? 2 * NG : mp * NG;           // head seg base (== tl base)
  int tb = (mp == 0) ? 0 : (mp == 1) ? NG : NG + NP;  // tr seg base
  // |tl+tr| <= sum|qw| ~ 10 -> exp safe in fp32 without max-shift.
  float ex = expf((tl3[hb + s] + tr3[tb + d]) * sharp[mp]);
  int node = hb + s;
  int pos = offsets[node] + atomicAdd(&cnt[node], 1);
  rec[pos] = make_uint2((unsigned)d, __float_as_uint(ex));
}

// ------- gather over concatenated node space, wave per head node ----------
__global__ __launch_bounds__(256) void gather3_kernel(
    const ushort* __restrict__ rb_gene, const ushort* __restrict__ rb_prot,
    const int* __restrict__ offsets, const uint2* __restrict__ rec,
    float* __restrict__ out_gene, float* __restrict__ agg_gp,
    float* __restrict__ out_prot, int NG, int NP) {
  int lane = threadIdx.x & 63;
  int node = blockIdx.x * 4 + (threadIdx.x >> 6);
  const int NT = 2 * NG + NP;
  if (node >= NT) return;

  const ushort* rt;
  float* outp;
  if (node < NG) {
    rt = rb_gene; outp = out_gene + (size_t)node * 128;
  } else if (node < 2 * NG) {
    rt = rb_prot; outp = agg_gp + (size_t)(node - NG) * 128;
  } else {
    rt = rb_prot; outp = out_prot + (size_t)(node - 2 * NG) * 128;
  }
  int j0 = offsets[node], j1 = offsets[node + 1];

  float ax = 0.f, ay = 0.f, dsum = 0.f;
  for (int base = j0; base < j1; base += 64) {
    int cntc = min(64, j1 - base);
    uint2 my = make_uint2(0u, 0u);
    if (lane < cntc) {
      my = rec[base + lane];
      dsum += __uint_as_float(my.y);
    }
    for (int k = 0; k < cntc; ++k) {
      int d = __shfl((int)my.x, k, 64);
      float w = __shfl(__uint_as_float(my.y), k, 64);
      unsigned v = *(const unsigned*)(rt + (size_t)d * 128 + lane * 2);
      ax += b2f_lo(v) * w;
      ay += b2f_hi(v) * w;
    }
  }
#pragma unroll
  for (int m = 32; m >= 1; m >>= 1) dsum += __shfl_xor(dsum, m, 64);
  float inv = 1.f / (dsum + 1e-16f);
  *(float2*)(outp + lane * 2) = make_float2(ax * inv, ay * inv);
}

// ------------- relation combine: softmax over R relations, ReLU ------------
template <int R>
__global__ __launch_bounds__(256) void combine_kernel(
    const float* __restrict__ rel0, const float* __restrict__ rel1,
    const ushort* __restrict__ selfb, const float* __restrict__ convW,
    const float* __restrict__ convb, float* __restrict__ out, int N) {
  int lane = threadIdx.x & 63;
  int node = blockIdx.x * 4 + (threadIdx.x >> 6);
  if (node >= N) return;
  int c = lane * 2;
  const float w0 = convW[c], w1 = convW[c + 1];

  float2 v[R];
  v[0] = *(const float2*)(rel0 + (size_t)node * 128 + c);
  if constexpr (R == 3) v[1] = *(const float2*)(rel1 + (size_t)node * 128 + c);
  {
    unsigned sv = *(const unsigned*)(selfb + (size_t)node * 128 + c);
    v[R - 1] = make_float2(b2f_lo(sv), b2f_hi(sv));
  }
  float s[R];
#pragma unroll
  for (int r = 0; r < R; ++r) {
    float p = v[r].x * w0 + v[r].y * w1;
#pragma unroll
    for (int m = 32; m >= 1; m >>= 1) p += __shfl_xor(p, m, 64);
    s[r] = p + convb[0];
  }
  float mx = s[0];
#pragma unroll
  for (int r = 1; r < R; ++r) mx = fmaxf(mx, s[r]);
  float es[R], sum = 0.f;
#pragma unroll
  for (int r = 0; r < R; ++r) { es[r] = expf(s[r] - mx); sum += es[r]; }
  float ox = 0.f, oy = 0.f;
#pragma unroll
  for (int r = 0; r < R; ++r) {
    float b = es[r] / sum;
    ox += v[r].x * b;
    oy += v[r].y * b;
  }
  *(float2*)(out + (size_t)node * 128 + c) =
      make_float2(fmaxf(ox, 0.f), fmaxf(oy, 0.f));
}

// ---------------------------------------------------------------------------
extern "C" void kernel_launch(void* const* d_in, const int* in_sizes, int n_in,
                              void* d_out, int out_size, void* d_ws,
                              size_t ws_size, hipStream_t stream) {
  const float* x_gene  = (const float*)d_in[0];
  const float* x_prot  = (const float*)d_in[1];
  const float* Wl_gene = (const float*)d_in[2];
  const float* bl_gene = (const float*)d_in[3];
  const float* Wr_gene = (const float*)d_in[4];
  const float* br_gene = (const float*)d_in[5];
  const float* Wl_prot = (const float*)d_in[6];
  const float* bl_prot = (const float*)d_in[7];
  const float* Wr_prot = (const float*)d_in[8];
  const float* br_prot = (const float*)d_in[9];
  const float* alW     = (const float*)d_in[10];  // [3,32,128] contiguous
  const float* alb     = (const float*)d_in[11];  // [3,32] contiguous
  const float* arW     = (const float*)d_in[12];
  const float* arb     = (const float*)d_in[13];
  const float* qw      = (const float*)d_in[14];  // [3,64,1]
  const float* sharp   = (const float*)d_in[15];
  const float* cgW     = (const float*)d_in[16];
  const float* cgb     = (const float*)d_in[17];
  const float* cpW     = (const float*)d_in[18];
  const float* cpb     = (const float*)d_in[19];
  const int* e_gg      = (const int*)d_in[20];
  const int* e_gp      = (const int*)d_in[21];
  const int* e_pp      = (const int*)d_in[22];

  const int NG = in_sizes[0] / 256;
  const int NP = in_sizes[1] / 256;
  const int E  = in_sizes[20] / 2;
  const int NPG = (NG + 127) & ~127;
  const int NPP = (NP + 127) & ~127;
  const int NT = 2 * NG + NP;          // concatenated head-node space
  const int NR = NG + 2 * NP;          // concatenated tail-node space (tr)

  char* base = (char*)d_ws;
  size_t off = 0;
  auto alloc = [&](size_t bytes) {
    void* p = base + off;
    off = (off + bytes + 255) & ~(size_t)255;
    return p;
  };
  ushort* xb_gene = (ushort*)alloc((size_t)NPG * 256 * 2);
  ushort* xb_prot = (ushort*)alloc((size_t)NPP * 256 * 2);
  // aliases over xb region (valid after proj phase; 96*4=384 < 512 B/row)
  float* al_gene = (float*)xb_gene;                 // [NPG,64] = al0|al1
  float* ar_gene = al_gene + (size_t)NPG * 64;      // [NPG,32]
  float* al_prot = ar_gene + (size_t)NPG * 32;      // [NPP,32]
  float* ar_prot = al_prot + (size_t)NPP * 32;      // [NPP,64] = ar1|ar2

  ushort* Wlr_gene = (ushort*)alloc(256 * 256 * 2);
  ushort* Wlr_prot = (ushort*)alloc(256 * 256 * 2);
  ushort* alWb     = (ushort*)alloc(96 * 128 * 2);
  ushort* arWb     = (ushort*)alloc(96 * 128 * 2);
  ushort* lb_gene  = (ushort*)alloc((size_t)NPG * 128 * 2);
  ushort* rb_gene  = (ushort*)alloc((size_t)NPG * 128 * 2);
  ushort* lb_prot  = (ushort*)alloc((size_t)NPP * 128 * 2);
  ushort* rb_prot  = (ushort*)alloc((size_t)NPP * 128 * 2);
  float*  agg_gp   = (float*)alloc((size_t)NG * 128 * 4);
  int*    deg      = (int*)alloc(2 * (size_t)NT * 4);  // deg+cnt: one memset
  int*    cnt      = deg + NT;
  int*    offsets  = (int*)alloc((size_t)(NT + 1) * 4);
  const int TILES  = (NT + 2047) / 2048;
  int*    tile_tot = (int*)alloc((size_t)TILES * 4);
  int*    tile_pre = (int*)alloc((size_t)TILES * 4);
  uint2*  rec      = (uint2*)alloc((size_t)(3 * E) * 8);
  float*  tl3      = (float*)alloc((size_t)NT * 4);
  float*  tr3      = (float*)alloc((size_t)NR * 4);

  float* out_gene = (float*)d_out;
  float* out_prot = out_gene + (size_t)NG * 128;

  dim3 blk(256);
  auto cvt_grid = [](int total) { return (total / 4 + 255) / 256; };

  // ---- 0) bf16 conversions ----
  cvt_bf16_kernel<<<cvt_grid(NPG * 256), blk, 0, stream>>>(x_gene, xb_gene, NG * 256, NPG * 256);
  cvt_bf16_kernel<<<cvt_grid(NPP * 256), blk, 0, stream>>>(x_prot, xb_prot, NP * 256, NPP * 256);
  cvt_bf16_kernel<<<cvt_grid(128 * 256), blk, 0, stream>>>(Wl_gene, Wlr_gene, 128 * 256, 128 * 256);
  cvt_bf16_kernel<<<cvt_grid(128 * 256), blk, 0, stream>>>(Wr_gene, Wlr_gene + 128 * 256, 128 * 256, 128 * 256);
  cvt_bf16_kernel<<<cvt_grid(128 * 256), blk, 0, stream>>>(Wl_prot, Wlr_prot, 128 * 256, 128 * 256);
  cvt_bf16_kernel<<<cvt_grid(128 * 256), blk, 0, stream>>>(Wr_prot, Wlr_prot + 128 * 256, 128 * 256, 128 * 256);
  cvt_bf16_kernel<<<cvt_grid(96 * 128), blk, 0, stream>>>(alW, alWb, 96 * 128, 96 * 128);
  cvt_bf16_kernel<<<cvt_grid(96 * 128), blk, 0, stream>>>(arW, arWb, 96 * 128, 96 * 128);

  // ---- 1) fused l/r projections (MFMA) ----
  proj_lr_mfma<<<dim3(NPG / 128, 2), blk, 0, stream>>>(xb_gene, Wlr_gene, bl_gene, br_gene, lb_gene, rb_gene, NG);
  proj_lr_mfma<<<dim3(NPP / 128, 2), blk, 0, stream>>>(xb_prot, Wlr_prot, bl_prot, br_prot, lb_prot, rb_prot, NP);

  // ---- 2) attention projections (MFMA); outputs overlay dead xb region ----
  attn_proj_mfma<64><<<NPG / 128, blk, 0, stream>>>(lb_gene, alWb, alb, al_gene, NG);                  // al0|al1
  attn_proj_mfma<32><<<NPG / 128, blk, 0, stream>>>(rb_gene, arWb, arb, ar_gene, NG);                  // ar0
  attn_proj_mfma<32><<<NPP / 128, blk, 0, stream>>>(lb_prot, alWb + 64 * 128, alb + 64, al_prot, NP);  // al2
  attn_proj_mfma<64><<<NPP / 128, blk, 0, stream>>>(rb_prot, arWb + 32 * 128, arb + 32, ar_prot, NP);  // ar1|ar2

  // ---- 3) per-node tanh-dot scalars (exact split of the edge logit) ----
  // tl3 layout: [gg genes | gp genes | pp prots]; tr3: [gg genes | gp prots | pp prots]
  const int gridTG = (NG + 7) / 8, gridTP = (NP + 7) / 8;
  tanh_dot_kernel<<<gridTG, blk, 0, stream>>>(al_gene,      64, qw + 0,        tl3,                NG);
  tanh_dot_kernel<<<gridTG, blk, 0, stream>>>(ar_gene,      32, qw + 32,       tr3,                NG);
  tanh_dot_kernel<<<gridTG, blk, 0, stream>>>(al_gene + 32, 64, qw + 64,       tl3 + NG,           NG);
  tanh_dot_kernel<<<gridTP, blk, 0, stream>>>(ar_prot,      64, qw + 64 + 32,  tr3 + NG,           NP);
  tanh_dot_kernel<<<gridTP, blk, 0, stream>>>(al_prot,      32, qw + 128,      tl3 + 2 * NG,       NP);
  tanh_dot_kernel<<<gridTP, blk, 0, stream>>>(ar_prot + 32, 64, qw + 128 + 32, tr3 + NG + NP,      NP);

  // ---- 4) batched CSR build + edge stage over all 3 metapaths ----
  const int gridE3 = (3 * E + 255) / 256;
  hipMemsetAsync(deg, 0, 2 * (size_t)NT * sizeof(int), stream);
  hist3_kernel<<<gridE3, blk, 0, stream>>>(e_gg, e_gp, e_pp, deg, E, NG);
  scanA_kernel<<<TILES, blk, 0, stream>>>(deg, offsets, tile_tot, NT);
  scanB_kernel<<<1, blk, 0, stream>>>(tile_tot, tile_pre, offsets, TILES, NT);
  scanC_kernel<<<TILES, blk, 0, stream>>>(offsets, tile_pre, NT);
  edge_logits3<<<gridE3, blk, 0, stream>>>(tl3, tr3, e_gg, e_gp, e_pp, sharp,
                                           offsets, cnt, rec, E, NG, NP);
  gather3_kernel<<<(NT + 3) / 4, blk, 0, stream>>>(rb_gene, rb_prot, offsets, rec,
                                                   out_gene, agg_gp, out_prot, NG, NP);

  // ---- 5) combine ----
  combine_kernel<3><<<(NG + 3) / 4, blk, 0, stream>>>(out_gene, agg_gp, lb_gene, cgW, cgb, out_gene, NG);
  combine_kernel<2><<<(NP + 3) / 4, blk, 0, stream>>>(out_prot, nullptr, lb_prot, cpW, cpb, out_prot, NP);
}

// Round 8
// 507.229 us; speedup vs baseline: 6.7017x; 1.1892x over previous
//
#include <hip/hip_runtime.h>
#include <hip/hip_bf16.h>

// ---------------------------------------------------------------------------
// LATTE heterogeneous GNN layer (gene/protein).
// R8: R7's batching (11 dispatches) + fused gather/combine, but the gather
//     inner loop reverted to the R6-PROVEN full-wave pattern: wave-uniform
//     trip counts, 4B/lane row loads, shuffle broadcast with uniform k,
//     2-wide unroll for ILP. (R7's half-wave divergent-k loop failed on HW.)
// ---------------------------------------------------------------------------

typedef __attribute__((ext_vector_type(8))) short short8;   // 8 bf16
typedef __attribute__((ext_vector_type(4))) float floatx4;  // 4 f32 acc

__device__ __forceinline__ void gload16(const void* g, void* l) {
  __builtin_amdgcn_global_load_lds(
      (const __attribute__((address_space(1))) void*)g,
      (__attribute__((address_space(3))) void*)l, 16, 0, 0);
}

__device__ __forceinline__ ushort f2b(float x) {
  __hip_bfloat16 h = __float2bfloat16(x);
  return *reinterpret_cast<ushort*>(&h);
}
__device__ __forceinline__ float b2f_lo(unsigned v) { return __uint_as_float(v << 16); }
__device__ __forceinline__ float b2f_hi(unsigned v) { return __uint_as_float(v & 0xffff0000u); }

// ---------------- batched fp32 -> bf16 convert (8 tensors) -----------------
struct CvtArgs {
  const float* src[8];
  ushort* dst[8];
  int valid[8];
  int total[8];
  int bstart[9];
};
__global__ __launch_bounds__(256) void cvt_multi(CvtArgs a) {
  int b = blockIdx.x;
  int e = 0;
#pragma unroll
  for (int j = 1; j < 8; ++j)
    if (b >= a.bstart[j]) e = j;
  int i = ((b - a.bstart[e]) * 256 + threadIdx.x) * 4;
  if (i >= a.total[e]) return;
  float4 v = make_float4(0.f, 0.f, 0.f, 0.f);
  if (i < a.valid[e]) v = *(const float4*)(a.src[e] + i);
  ushort4 o;
  o.x = f2b(v.x); o.y = f2b(v.y); o.z = f2b(v.z); o.w = f2b(v.w);
  *(ushort4*)(a.dst[e] + i) = o;
}

// ------------- fused l/r projection: [NPAD,256]bf16 @ [256,256]^T ----------
// grid: (rows/128, colHalf(2), nodeType(2))
struct ProjArgs {
  const ushort* xb[2];
  const ushort* Wb[2];
  const float* bl[2];
  const float* br[2];
  ushort* lb[2];
  ushort* rb[2];
  int N[2];
};
__global__ __launch_bounds__(256) void proj_lr_mfma(ProjArgs g) {
  const int ty = blockIdx.z;
  const ushort* xb = g.xb[ty];
  __shared__ ushort As[128 * 32];
  __shared__ ushort Bs[128 * 32];
  const int tid = threadIdx.x;
  const int lane = tid & 63;
  const int wave = tid >> 6;
  const int wm = wave & 1, wn = wave >> 1;
  const int rowBase = blockIdx.x * 128;
  const int colHalf = blockIdx.y;
  const ushort* Wbase = g.Wb[ty] + (size_t)colHalf * 128 * 256;

  floatx4 acc[4][4] = {};

  const int srow = tid >> 2, schk = tid & 3;
  for (int k0 = 0; k0 < 256; k0 += 32) {
#pragma unroll
    for (int i = 0; i < 2; ++i) {
      gload16(xb + (size_t)(rowBase + srow + i * 64) * 256 + k0 + schk * 8,
              &As[(tid + i * 256) * 8]);
      gload16(Wbase + (size_t)(srow + i * 64) * 256 + k0 + schk * 8,
              &Bs[(tid + i * 256) * 8]);
    }
    __syncthreads();
    short8 bf[4];
#pragma unroll
    for (int nt = 0; nt < 4; ++nt)
      bf[nt] = *(const short8*)&Bs[(wn * 64 + nt * 16 + (lane & 15)) * 32 + (lane >> 4) * 8];
#pragma unroll
    for (int mt = 0; mt < 4; ++mt) {
      short8 a = *(const short8*)&As[(wm * 64 + mt * 16 + (lane & 15)) * 32 + (lane >> 4) * 8];
#pragma unroll
      for (int nt = 0; nt < 4; ++nt)
        acc[mt][nt] = __builtin_amdgcn_mfma_f32_16x16x32_bf16(a, bf[nt], acc[mt][nt], 0, 0, 0);
    }
    __syncthreads();
  }

  const int N = g.N[ty];
  const float* bias = colHalf ? g.br[ty] : g.bl[ty];
  ushort* outp = colHalf ? g.rb[ty] : g.lb[ty];
#pragma unroll
  for (int mt = 0; mt < 4; ++mt)
#pragma unroll
    for (int nt = 0; nt < 4; ++nt) {
      int col = wn * 64 + nt * 16 + (lane & 15);
      float bv = bias[col];
#pragma unroll
      for (int vi = 0; vi < 4; ++vi) {
        int row = rowBase + wm * 64 + mt * 16 + (lane >> 4) * 4 + vi;
        if (row < N) outp[(size_t)row * 128 + col] = f2b(acc[mt][nt][vi] + bv);
      }
    }
}

// ------------- batched attention projection (4 GEMMs), grid.y = entry ------
struct AttnArgs {
  const ushort* Ab[4];
  const ushort* Wb[4];
  const float* bias[4];
  float* out[4];
  int N[4];
  int BN[4];
};
__global__ __launch_bounds__(256) void attn_proj_multi(AttnArgs g) {
  const int ei = blockIdx.y;
  const ushort* Ab = g.Ab[ei];
  const ushort* Wb = g.Wb[ei];
  const int N = g.N[ei], BN = g.BN[ei];
  const int NB = BN >> 4;  // 2 or 4 tiles of 16 cols
  __shared__ ushort As[128 * 32];
  __shared__ ushort Ws[64 * 128];
  const int tid = threadIdx.x;
  const int lane = tid & 63;
  const int wave = tid >> 6;
  const int rowBase = blockIdx.x * 128;

  for (int i = 0; i < NB; ++i) {
    int idx = tid + i * 256;
    gload16(Wb + (size_t)idx * 8, &Ws[idx * 8]);
  }

  floatx4 acc[2][4] = {};
  for (int k0 = 0; k0 < 128; k0 += 32) {
#pragma unroll
    for (int i = 0; i < 2; ++i) {
      int t = tid + i * 256;
      gload16(Ab + (size_t)(rowBase + (t >> 2)) * 128 + k0 + (t & 3) * 8, &As[t * 8]);
    }
    __syncthreads();
    short8 bf[4];
#pragma unroll
    for (int nt = 0; nt < 4; ++nt)
      if (nt < NB)
        bf[nt] = *(const short8*)&Ws[(nt * 16 + (lane & 15)) * 128 + k0 + (lane >> 4) * 8];
#pragma unroll
    for (int mt = 0; mt < 2; ++mt) {
      short8 a = *(const short8*)&As[(wave * 32 + mt * 16 + (lane & 15)) * 32 + (lane >> 4) * 8];
#pragma unroll
      for (int nt = 0; nt < 4; ++nt)
        if (nt < NB)
          acc[mt][nt] = __builtin_amdgcn_mfma_f32_16x16x32_bf16(a, bf[nt], acc[mt][nt], 0, 0, 0);
    }
    __syncthreads();
  }
  const float* bias = g.bias[ei];
  float* out = g.out[ei];
#pragma unroll
  for (int mt = 0; mt < 2; ++mt)
#pragma unroll
    for (int nt = 0; nt < 4; ++nt) {
      if (nt >= NB) continue;
      int col = nt * 16 + (lane & 15);
      float bv = bias[col];
#pragma unroll
      for (int vi = 0; vi < 4; ++vi) {
        int row = rowBase + wave * 32 + mt * 16 + (lane >> 4) * 4 + vi;
        if (row < N) out[(size_t)row * BN + col] = acc[mt][nt][vi] + bv;
      }
    }
}

// ------- batched per-node tanh-dot (6 entries) ----------------------------
struct TanhArgs {
  const float* a[6];
  const float* q[6];
  float* out[6];
  int stride[6];
  int N[6];
  int bstart[7];
};
__global__ __launch_bounds__(256) void tanh_multi(TanhArgs t) {
  int b = blockIdx.x;
  int e = 0;
#pragma unroll
  for (int j = 1; j < 6; ++j)
    if (b >= t.bstart[j]) e = j;
  int lane32 = threadIdx.x & 31;
  int node = (b - t.bstart[e]) * 8 + (threadIdx.x >> 5);
  if (node >= t.N[e]) return;
  float p = tanhf(t.a[e][(size_t)node * t.stride[e] + lane32]) * t.q[e][lane32];
#pragma unroll
  for (int m = 16; m >= 1; m >>= 1) p += __shfl_xor(p, m, 32);
  if (lane32 == 0) t.out[e][node] = p;
}

// ------- hist over all 3 edge lists into concatenated head-node space -----
__global__ __launch_bounds__(256) void hist3_kernel(
    const int* __restrict__ e0, const int* __restrict__ e1,
    const int* __restrict__ e2, int* __restrict__ deg, int E, int NG) {
  int e = blockIdx.x * 256 + threadIdx.x;
  if (e >= 3 * E) return;
  int mp = (e >= 2 * E) ? 2 : ((e >= E) ? 1 : 0);
  int el = e - mp * E;
  const int* ep = (mp == 0) ? e0 : (mp == 1) ? e1 : e2;
  int segb = (mp == 2) ? 2 * NG : mp * NG;
  atomicAdd(&deg[segb + ep[el]], 1);
}

// ------- hierarchical scan: A) tile scan, B) partials, C) add prefix ------
__global__ __launch_bounds__(256) void scanA_kernel(
    const int* __restrict__ deg, int* __restrict__ offsets,
    int* __restrict__ tile_tot, int n) {
  __shared__ int wtot[4];
  const int t = threadIdx.x;
  const int base = blockIdx.x * 2048 + t * 8;
  int v[8], pre[8], s = 0;
#pragma unroll
  for (int j = 0; j < 8; ++j) {
    v[j] = (base + j < n) ? deg[base + j] : 0;
    pre[j] = s;
    s += v[j];
  }
  const int lane = t & 63, wv = t >> 6;
  int x = s;
#pragma unroll
  for (int o = 1; o < 64; o <<= 1) {
    int u = __shfl_up(x, o, 64);
    if (lane >= o) x += u;
  }
  if (lane == 63) wtot[wv] = x;
  __syncthreads();
  int wpre = 0;
#pragma unroll
  for (int j = 0; j < 4; ++j) wpre += (j < wv) ? wtot[j] : 0;
  int excl = wpre + x - s;
#pragma unroll
  for (int j = 0; j < 8; ++j)
    if (base + j < n) offsets[base + j] = excl + pre[j];
  if (t == 255) tile_tot[blockIdx.x] = wpre + x;
}

__global__ __launch_bounds__(256) void scanB_kernel(
    const int* __restrict__ tile_tot, int* __restrict__ tile_pre,
    int* __restrict__ offsets, int T, int n) {
  __shared__ int wtot[4];
  const int t = threadIdx.x;
  int v = (t < T) ? tile_tot[t] : 0;
  const int lane = t & 63, wv = t >> 6;
  int x = v;
#pragma unroll
  for (int o = 1; o < 64; o <<= 1) {
    int u = __shfl_up(x, o, 64);
    if (lane >= o) x += u;
  }
  if (lane == 63) wtot[wv] = x;
  __syncthreads();
  int wpre = 0;
#pragma unroll
  for (int j = 0; j < 4; ++j) wpre += (j < wv) ? wtot[j] : 0;
  if (t < T) tile_pre[t] = wpre + x - v;
  if (t == 255) offsets[n] = wpre + x;  // grand total
}

__global__ __launch_bounds__(256) void scanC_kernel(
    int* __restrict__ offsets, const int* __restrict__ tile_pre, int n) {
  const int add = tile_pre[blockIdx.x];
  const int base = blockIdx.x * 2048 + threadIdx.x * 8;
#pragma unroll
  for (int j = 0; j < 8; ++j)
    if (base + j < n) offsets[base + j] += add;
}

// ------- edge logits + sorted scatter over all 3 metapaths ----------------
__global__ __launch_bounds__(256) void edge_logits3(
    const float* __restrict__ tl3, const float* __restrict__ tr3,
    const int* __restrict__ e0, const int* __restrict__ e1,
    const int* __restrict__ e2, const float* __restrict__ sharp,
    const int* __restrict__ offsets, int* __restrict__ cnt,
    uint2* __restrict__ rec, int E, int NG, int NP) {
  int e = blockIdx.x * 256 + threadIdx.x;
  if (e >= 3 * E) return;
  int mp = (e >= 2 * E) ? 2 : ((e >= E) ? 1 : 0);
  int el = e - mp * E;
  const int* ep = (mp == 0) ? e0 : (mp == 1) ? e1 : e2;
  int s = ep[el], d = ep[el + E];
  int hb = (mp == 2) ? 2 * NG : mp * NG;              // head seg base
  int tb = (mp == 0) ? 0 : (mp == 1) ? NG : NG + NP;  // tr seg base
  // |tl+tr| <= sum|qw| ~ 10 -> exp safe in fp32 without max-shift.
  float ex = expf((tl3[hb + s] + tr3[tb + d]) * sharp[mp]);
  int node = hb + s;
  int pos = offsets[node] + atomicAdd(&cnt[node], 1);
  rec[pos] = make_uint2((unsigned)d, __float_as_uint(ex));
}

// ------- fused gather + relation combine: wave per OUTPUT node ------------
// R6-proven inner loop: full wave per edge (4B/lane), wave-uniform k,
// unrolled 2-wide for two independent row-loads in flight.
__global__ __launch_bounds__(256) void gather_combine(
    const ushort* __restrict__ rb_gene, const ushort* __restrict__ rb_prot,
    const ushort* __restrict__ lb_gene, const ushort* __restrict__ lb_prot,
    const int* __restrict__ offsets, const uint2* __restrict__ rec,
    const float* __restrict__ cgW, const float* __restrict__ cgb,
    const float* __restrict__ cpW, const float* __restrict__ cpb,
    float* __restrict__ out_gene, float* __restrict__ out_prot,
    int NG, int NP) {
  const int lane = threadIdx.x & 63;
  const int node = blockIdx.x * 4 + (threadIdx.x >> 6);
  if (node >= NG + NP) return;
  const bool isGene = node < NG;

  float a0x = 0.f, a0y = 0.f, a1x = 0.f, a1y = 0.f;
  float ds0 = 0.f, ds1 = 0.f;

  for (int r = 0; r < 2; ++r) {
    if (r == 1 && !isGene) break;
    const int h = (r == 0 && isGene) ? node : NG + node;  // concatenated head
    const ushort* rt = (isGene && r == 0) ? rb_gene : rb_prot;
    const int j0 = offsets[h], j1 = offsets[h + 1];
    float ax = 0.f, ay = 0.f, ds = 0.f;
    for (int bj = j0; bj < j1; bj += 64) {
      const int cc = min(64, j1 - bj);
      uint2 my = make_uint2(0u, 0u);
      if (lane < cc) {
        my = rec[bj + lane];
        ds += __uint_as_float(my.y);
      }
      int k = 0;
      for (; k + 1 < cc; k += 2) {  // wave-uniform: 2 loads in flight
        int d0 = __shfl((int)my.x, k, 64);
        float w0 = __shfl(__uint_as_float(my.y), k, 64);
        int d1 = __shfl((int)my.x, k + 1, 64);
        float w1 = __shfl(__uint_as_float(my.y), k + 1, 64);
        unsigned v0 = *(const unsigned*)(rt + (size_t)d0 * 128 + lane * 2);
        unsigned v1 = *(const unsigned*)(rt + (size_t)d1 * 128 + lane * 2);
        ax += b2f_lo(v0) * w0 + b2f_lo(v1) * w1;
        ay += b2f_hi(v0) * w0 + b2f_hi(v1) * w1;
      }
      if (k < cc) {
        int d = __shfl((int)my.x, k, 64);
        float w = __shfl(__uint_as_float(my.y), k, 64);
        unsigned v = *(const unsigned*)(rt + (size_t)d * 128 + lane * 2);
        ax += b2f_lo(v) * w;
        ay += b2f_hi(v) * w;
      }
    }
    if (r == 0) { a0x = ax; a0y = ay; ds0 = ds; }
    else        { a1x = ax; a1y = ay; ds1 = ds; }
  }

#pragma unroll
  for (int m = 32; m >= 1; m >>= 1) {
    ds0 += __shfl_xor(ds0, m, 64);
    ds1 += __shfl_xor(ds1, m, 64);
  }
  const float inv0 = 1.f / (ds0 + 1e-16f);
  const float inv1 = 1.f / (ds1 + 1e-16f);
  const float g0x = a0x * inv0, g0y = a0y * inv0;
  const float g1x = a1x * inv1, g1y = a1y * inv1;

  const ushort* lbp = isGene ? lb_gene + (size_t)node * 128
                             : lb_prot + (size_t)(node - NG) * 128;
  unsigned sv = *(const unsigned*)(lbp + lane * 2);
  const float sx = b2f_lo(sv), sy = b2f_hi(sv);

  const float* cW = isGene ? cgW : cpW;
  const float cb = isGene ? cgb[0] : cpb[0];
  const float w0 = cW[lane * 2], w1 = cW[lane * 2 + 1];
  float p0 = g0x * w0 + g0y * w1;
  float p1 = g1x * w0 + g1y * w1;
  float ps = sx * w0 + sy * w1;
#pragma unroll
  for (int m = 32; m >= 1; m >>= 1) {
    p0 += __shfl_xor(p0, m, 64);
    p1 += __shfl_xor(p1, m, 64);
    ps += __shfl_xor(ps, m, 64);
  }
  const float s0 = p0 + cb, s1 = p1 + cb, ss = ps + cb;
  const float mx = isGene ? fmaxf(fmaxf(s0, s1), ss) : fmaxf(s0, ss);
  const float e0 = expf(s0 - mx);
  const float e1 = isGene ? expf(s1 - mx) : 0.f;
  const float es = expf(ss - mx);
  const float sum = e0 + e1 + es;
  const float b0 = e0 / sum, b1 = e1 / sum, bs = es / sum;

  const float ox = fmaxf(g0x * b0 + g1x * b1 + sx * bs, 0.f);
  const float oy = fmaxf(g0y * b0 + g1y * b1 + sy * bs, 0.f);
  float* op = isGene ? out_gene + (size_t)node * 128
                     : out_prot + (size_t)(node - NG) * 128;
  *(float2*)(op + lane * 2) = make_float2(ox, oy);
}

// ---------------------------------------------------------------------------
extern "C" void kernel_launch(void* const* d_in, const int* in_sizes, int n_in,
                              void* d_out, int out_size, void* d_ws,
                              size_t ws_size, hipStream_t stream) {
  const float* x_gene  = (const float*)d_in[0];
  const float* x_prot  = (const float*)d_in[1];
  const float* Wl_gene = (const float*)d_in[2];
  const float* bl_gene = (const float*)d_in[3];
  const float* Wr_gene = (const float*)d_in[4];
  const float* br_gene = (const float*)d_in[5];
  const float* Wl_prot = (const float*)d_in[6];
  const float* bl_prot = (const float*)d_in[7];
  const float* Wr_prot = (const float*)d_in[8];
  const float* br_prot = (const float*)d_in[9];
  const float* alW     = (const float*)d_in[10];  // [3,32,128] contiguous
  const float* alb     = (const float*)d_in[11];  // [3,32] contiguous
  const float* arW     = (const float*)d_in[12];
  const float* arb     = (const float*)d_in[13];
  const float* qw      = (const float*)d_in[14];  // [3,64,1]
  const float* sharp   = (const float*)d_in[15];
  const float* cgW     = (const float*)d_in[16];
  const float* cgb     = (const float*)d_in[17];
  const float* cpW     = (const float*)d_in[18];
  const float* cpb     = (const float*)d_in[19];
  const int* e_gg      = (const int*)d_in[20];
  const int* e_gp      = (const int*)d_in[21];
  const int* e_pp      = (const int*)d_in[22];

  const int NG = in_sizes[0] / 256;
  const int NP = in_sizes[1] / 256;
  const int E  = in_sizes[20] / 2;
  const int NPG = (NG + 127) & ~127;
  const int NPP = (NP + 127) & ~127;
  const int NT = 2 * NG + NP;          // concatenated head-node space
  const int NR = NG + 2 * NP;          // concatenated tail-node space (tr)

  char* base = (char*)d_ws;
  size_t off = 0;
  auto alloc = [&](size_t bytes) {
    void* p = base + off;
    off = (off + bytes + 255) & ~(size_t)255;
    return p;
  };
  ushort* xb_gene = (ushort*)alloc((size_t)NPG * 256 * 2);
  ushort* xb_prot = (ushort*)alloc((size_t)NPP * 256 * 2);
  // aliases over xb region (valid after proj phase; 96*4=384 < 512 B/row)
  float* al_gene = (float*)xb_gene;                 // [NPG,64] = al0|al1
  float* ar_gene = al_gene + (size_t)NPG * 64;      // [NPG,32]
  float* al_prot = ar_gene + (size_t)NPG * 32;      // [NPP,32]
  float* ar_prot = al_prot + (size_t)NPP * 32;      // [NPP,64] = ar1|ar2

  ushort* Wlr_gene = (ushort*)alloc(256 * 256 * 2);
  ushort* Wlr_prot = (ushort*)alloc(256 * 256 * 2);
  ushort* alWb     = (ushort*)alloc(96 * 128 * 2);
  ushort* arWb     = (ushort*)alloc(96 * 128 * 2);
  ushort* lb_gene  = (ushort*)alloc((size_t)NPG * 128 * 2);
  ushort* rb_gene  = (ushort*)alloc((size_t)NPG * 128 * 2);
  ushort* lb_prot  = (ushort*)alloc((size_t)NPP * 128 * 2);
  ushort* rb_prot  = (ushort*)alloc((size_t)NPP * 128 * 2);
  int*    deg      = (int*)alloc(2 * (size_t)NT * 4);  // deg+cnt: one memset
  int*    cnt      = deg + NT;
  int*    offsets  = (int*)alloc((size_t)(NT + 1) * 4);
  const int TILES  = (NT + 2047) / 2048;
  int*    tile_tot = (int*)alloc((size_t)TILES * 4);
  int*    tile_pre = (int*)alloc((size_t)TILES * 4);
  uint2*  rec      = (uint2*)alloc((size_t)(3 * E) * 8);
  float*  tl3      = (float*)alloc((size_t)NT * 4);
  float*  tr3      = (float*)alloc((size_t)NR * 4);

  float* out_gene = (float*)d_out;
  float* out_prot = out_gene + (size_t)NG * 128;

  dim3 blk(256);

  // ---- 0) batched bf16 conversions (1 dispatch) ----
  {
    CvtArgs a;
    const float* srcs[8] = {x_gene, x_prot, Wl_gene, Wr_gene, Wl_prot, Wr_prot, alW, arW};
    ushort* dsts[8] = {xb_gene, xb_prot, Wlr_gene, Wlr_gene + 128 * 256,
                       Wlr_prot, Wlr_prot + 128 * 256, alWb, arWb};
    int valids[8] = {NG * 256, NP * 256, 128 * 256, 128 * 256, 128 * 256, 128 * 256, 96 * 128, 96 * 128};
    int totals[8] = {NPG * 256, NPP * 256, 128 * 256, 128 * 256, 128 * 256, 128 * 256, 96 * 128, 96 * 128};
    int b = 0;
    for (int j = 0; j < 8; ++j) {
      a.src[j] = srcs[j]; a.dst[j] = dsts[j];
      a.valid[j] = valids[j]; a.total[j] = totals[j];
      a.bstart[j] = b;
      b += (totals[j] / 4 + 255) / 256;
    }
    a.bstart[8] = b;
    cvt_multi<<<b, blk, 0, stream>>>(a);
  }

  // ---- 1) fused l/r projections, both node types (1 dispatch) ----
  {
    ProjArgs p;
    p.xb[0] = xb_gene; p.xb[1] = xb_prot;
    p.Wb[0] = Wlr_gene; p.Wb[1] = Wlr_prot;
    p.bl[0] = bl_gene; p.bl[1] = bl_prot;
    p.br[0] = br_gene; p.br[1] = br_prot;
    p.lb[0] = lb_gene; p.lb[1] = lb_prot;
    p.rb[0] = rb_gene; p.rb[1] = rb_prot;
    p.N[0] = NG; p.N[1] = NP;
    proj_lr_mfma<<<dim3(NPG / 128, 2, 2), blk, 0, stream>>>(p);
  }

  // ---- 2) batched attention projections (1 dispatch) ----
  {
    AttnArgs a;
    a.Ab[0] = lb_gene; a.Wb[0] = alWb;            a.bias[0] = alb;      a.out[0] = al_gene; a.N[0] = NG; a.BN[0] = 64;
    a.Ab[1] = rb_gene; a.Wb[1] = arWb;            a.bias[1] = arb;      a.out[1] = ar_gene; a.N[1] = NG; a.BN[1] = 32;
    a.Ab[2] = lb_prot; a.Wb[2] = alWb + 64 * 128; a.bias[2] = alb + 64; a.out[2] = al_prot; a.N[2] = NP; a.BN[2] = 32;
    a.Ab[3] = rb_prot; a.Wb[3] = arWb + 32 * 128; a.bias[3] = arb + 32; a.out[3] = ar_prot; a.N[3] = NP; a.BN[3] = 64;
    attn_proj_multi<<<dim3(NPG / 128, 4), blk, 0, stream>>>(a);
  }

  // ---- 3) batched per-node tanh-dot scalars (1 dispatch) ----
  {
    TanhArgs t;
    const float* as[6] = {al_gene, ar_gene, al_gene + 32, ar_prot, al_prot, ar_prot + 32};
    const float* qs[6] = {qw + 0, qw + 32, qw + 64, qw + 96, qw + 128, qw + 160};
    float* outs[6] = {tl3, tr3, tl3 + NG, tr3 + NG, tl3 + 2 * NG, tr3 + NG + NP};
    int strides[6] = {64, 32, 64, 64, 32, 64};
    int Ns[6] = {NG, NG, NG, NP, NP, NP};
    int b = 0;
    for (int j = 0; j < 6; ++j) {
      t.a[j] = as[j]; t.q[j] = qs[j]; t.out[j] = outs[j];
      t.stride[j] = strides[j]; t.N[j] = Ns[j];
      t.bstart[j] = b;
      b += (Ns[j] + 7) / 8;
    }
    t.bstart[6] = b;
    tanh_multi<<<b, blk, 0, stream>>>(t);
  }

  // ---- 4) batched CSR build + edge stage over all 3 metapaths ----
  const int gridE3 = (3 * E + 255) / 256;
  hipMemsetAsync(deg, 0, 2 * (size_t)NT * sizeof(int), stream);
  hist3_kernel<<<gridE3, blk, 0, stream>>>(e_gg, e_gp, e_pp, deg, E, NG);
  scanA_kernel<<<TILES, blk, 0, stream>>>(deg, offsets, tile_tot, NT);
  scanB_kernel<<<1, blk, 0, stream>>>(tile_tot, tile_pre, offsets, TILES, NT);
  scanC_kernel<<<TILES, blk, 0, stream>>>(offsets, tile_pre, NT);
  edge_logits3<<<gridE3, blk, 0, stream>>>(tl3, tr3, e_gg, e_gp, e_pp, sharp,
                                           offsets, cnt, rec, E, NG, NP);

  // ---- 5) fused gather + relation combine (1 dispatch) ----
  gather_combine<<<(NG + NP + 3) / 4, blk, 0, stream>>>(
      rb_gene, rb_prot, lb_gene, lb_prot, offsets, rec,
      cgW, cgb, cpW, cpb, out_gene, out_prot, NG, NP);
}

// Round 9
// 459.919 us; speedup vs baseline: 7.3911x; 1.1029x over previous
//
#include <hip/hip_runtime.h>
#include <hip/hip_bf16.h>

// ---------------------------------------------------------------------------
// LATTE heterogeneous GNN layer (gene/protein).
// R9: CSR record is dst-only (4B). ex=expf((tl+tr)*sharp) computed inside
//     gather's record phase (64 edges in parallel, 1 lane each) -> the whole
//     edge_logits pass is gone. hist3 emits rank[e] (coalesced) so scatter3
//     needs no atomics. Gather: half-wave rows (32 lanes x 8B), 2 edges per
//     wave-iteration, 2-wide unroll, ALL shuffles in wave-uniform control
//     flow (R7's divergent-shuffle bug class is structurally excluded).
// ---------------------------------------------------------------------------

typedef __attribute__((ext_vector_type(8))) short short8;   // 8 bf16
typedef __attribute__((ext_vector_type(4))) float floatx4;  // 4 f32 acc

__device__ __forceinline__ void gload16(const void* g, void* l) {
  __builtin_amdgcn_global_load_lds(
      (const __attribute__((address_space(1))) void*)g,
      (__attribute__((address_space(3))) void*)l, 16, 0, 0);
}

__device__ __forceinline__ ushort f2b(float x) {
  __hip_bfloat16 h = __float2bfloat16(x);
  return *reinterpret_cast<ushort*>(&h);
}
__device__ __forceinline__ float b2f_lo(unsigned v) { return __uint_as_float(v << 16); }
__device__ __forceinline__ float b2f_hi(unsigned v) { return __uint_as_float(v & 0xffff0000u); }

// ---------------- batched fp32 -> bf16 convert (8 tensors) -----------------
struct CvtArgs {
  const float* src[8];
  ushort* dst[8];
  int valid[8];
  int total[8];
  int bstart[9];
};
__global__ __launch_bounds__(256) void cvt_multi(CvtArgs a) {
  int b = blockIdx.x;
  int e = 0;
#pragma unroll
  for (int j = 1; j < 8; ++j)
    if (b >= a.bstart[j]) e = j;
  int i = ((b - a.bstart[e]) * 256 + threadIdx.x) * 4;
  if (i >= a.total[e]) return;
  float4 v = make_float4(0.f, 0.f, 0.f, 0.f);
  if (i < a.valid[e]) v = *(const float4*)(a.src[e] + i);
  ushort4 o;
  o.x = f2b(v.x); o.y = f2b(v.y); o.z = f2b(v.z); o.w = f2b(v.w);
  *(ushort4*)(a.dst[e] + i) = o;
}

// ------------- fused l/r projection: [NPAD,256]bf16 @ [256,256]^T ----------
struct ProjArgs {
  const ushort* xb[2];
  const ushort* Wb[2];
  const float* bl[2];
  const float* br[2];
  ushort* lb[2];
  ushort* rb[2];
  int N[2];
};
__global__ __launch_bounds__(256) void proj_lr_mfma(ProjArgs g) {
  const int ty = blockIdx.z;
  const ushort* xb = g.xb[ty];
  __shared__ ushort As[128 * 32];
  __shared__ ushort Bs[128 * 32];
  const int tid = threadIdx.x;
  const int lane = tid & 63;
  const int wave = tid >> 6;
  const int wm = wave & 1, wn = wave >> 1;
  const int rowBase = blockIdx.x * 128;
  const int colHalf = blockIdx.y;
  const ushort* Wbase = g.Wb[ty] + (size_t)colHalf * 128 * 256;

  floatx4 acc[4][4] = {};

  const int srow = tid >> 2, schk = tid & 3;
  for (int k0 = 0; k0 < 256; k0 += 32) {
#pragma unroll
    for (int i = 0; i < 2; ++i) {
      gload16(xb + (size_t)(rowBase + srow + i * 64) * 256 + k0 + schk * 8,
              &As[(tid + i * 256) * 8]);
      gload16(Wbase + (size_t)(srow + i * 64) * 256 + k0 + schk * 8,
              &Bs[(tid + i * 256) * 8]);
    }
    __syncthreads();
    short8 bf[4];
#pragma unroll
    for (int nt = 0; nt < 4; ++nt)
      bf[nt] = *(const short8*)&Bs[(wn * 64 + nt * 16 + (lane & 15)) * 32 + (lane >> 4) * 8];
#pragma unroll
    for (int mt = 0; mt < 4; ++mt) {
      short8 a = *(const short8*)&As[(wm * 64 + mt * 16 + (lane & 15)) * 32 + (lane >> 4) * 8];
#pragma unroll
      for (int nt = 0; nt < 4; ++nt)
        acc[mt][nt] = __builtin_amdgcn_mfma_f32_16x16x32_bf16(a, bf[nt], acc[mt][nt], 0, 0, 0);
    }
    __syncthreads();
  }

  const int N = g.N[ty];
  const float* bias = colHalf ? g.br[ty] : g.bl[ty];
  ushort* outp = colHalf ? g.rb[ty] : g.lb[ty];
#pragma unroll
  for (int mt = 0; mt < 4; ++mt)
#pragma unroll
    for (int nt = 0; nt < 4; ++nt) {
      int col = wn * 64 + nt * 16 + (lane & 15);
      float bv = bias[col];
#pragma unroll
      for (int vi = 0; vi < 4; ++vi) {
        int row = rowBase + wm * 64 + mt * 16 + (lane >> 4) * 4 + vi;
        if (row < N) outp[(size_t)row * 128 + col] = f2b(acc[mt][nt][vi] + bv);
      }
    }
}

// ------------- batched attention projection (4 GEMMs), grid.y = entry ------
struct AttnArgs {
  const ushort* Ab[4];
  const ushort* Wb[4];
  const float* bias[4];
  float* out[4];
  int N[4];
  int BN[4];
};
__global__ __launch_bounds__(256) void attn_proj_multi(AttnArgs g) {
  const int ei = blockIdx.y;
  const ushort* Ab = g.Ab[ei];
  const ushort* Wb = g.Wb[ei];
  const int N = g.N[ei], BN = g.BN[ei];
  const int NB = BN >> 4;
  __shared__ ushort As[128 * 32];
  __shared__ ushort Ws[64 * 128];
  const int tid = threadIdx.x;
  const int lane = tid & 63;
  const int wave = tid >> 6;
  const int rowBase = blockIdx.x * 128;

  for (int i = 0; i < NB; ++i) {
    int idx = tid + i * 256;
    gload16(Wb + (size_t)idx * 8, &Ws[idx * 8]);
  }

  floatx4 acc[2][4] = {};
  for (int k0 = 0; k0 < 128; k0 += 32) {
#pragma unroll
    for (int i = 0; i < 2; ++i) {
      int t = tid + i * 256;
      gload16(Ab + (size_t)(rowBase + (t >> 2)) * 128 + k0 + (t & 3) * 8, &As[t * 8]);
    }
    __syncthreads();
    short8 bf[4];
#pragma unroll
    for (int nt = 0; nt < 4; ++nt)
      if (nt < NB)
        bf[nt] = *(const short8*)&Ws[(nt * 16 + (lane & 15)) * 128 + k0 + (lane >> 4) * 8];
#pragma unroll
    for (int mt = 0; mt < 2; ++mt) {
      short8 a = *(const short8*)&As[(wave * 32 + mt * 16 + (lane & 15)) * 32 + (lane >> 4) * 8];
#pragma unroll
      for (int nt = 0; nt < 4; ++nt)
        if (nt < NB)
          acc[mt][nt] = __builtin_amdgcn_mfma_f32_16x16x32_bf16(a, bf[nt], acc[mt][nt], 0, 0, 0);
    }
    __syncthreads();
  }
  const float* bias = g.bias[ei];
  float* out = g.out[ei];
#pragma unroll
  for (int mt = 0; mt < 2; ++mt)
#pragma unroll
    for (int nt = 0; nt < 4; ++nt) {
      if (nt >= NB) continue;
      int col = nt * 16 + (lane & 15);
      float bv = bias[col];
#pragma unroll
      for (int vi = 0; vi < 4; ++vi) {
        int row = rowBase + wave * 32 + mt * 16 + (lane >> 4) * 4 + vi;
        if (row < N) out[(size_t)row * BN + col] = acc[mt][nt][vi] + bv;
      }
    }
}

// ------- batched per-node tanh-dot (6 entries) ----------------------------
struct TanhArgs {
  const float* a[6];
  const float* q[6];
  float* out[6];
  int stride[6];
  int N[6];
  int bstart[7];
};
__global__ __launch_bounds__(256) void tanh_multi(TanhArgs t) {
  int b = blockIdx.x;
  int e = 0;
#pragma unroll
  for (int j = 1; j < 6; ++j)
    if (b >= t.bstart[j]) e = j;
  int lane32 = threadIdx.x & 31;
  int node = (b - t.bstart[e]) * 8 + (threadIdx.x >> 5);
  if (node >= t.N[e]) return;
  float p = tanhf(t.a[e][(size_t)node * t.stride[e] + lane32]) * t.q[e][lane32];
#pragma unroll
  for (int m = 16; m >= 1; m >>= 1) p += __shfl_xor(p, m, 32);
  if (lane32 == 0) t.out[e][node] = p;
}

// ------- hist + rank: deg count and per-edge rank (coalesced) -------------
__global__ __launch_bounds__(256) void hist3_kernel(
    const int* __restrict__ e0, const int* __restrict__ e1,
    const int* __restrict__ e2, int* __restrict__ deg,
    int* __restrict__ rank, int E, int NG) {
  int e = blockIdx.x * 256 + threadIdx.x;
  if (e >= 3 * E) return;
  int mp = (e >= 2 * E) ? 2 : ((e >= E) ? 1 : 0);
  int el = e - mp * E;
  const int* ep = (mp == 0) ? e0 : (mp == 1) ? e1 : e2;
  int segb = (mp == 2) ? 2 * NG : mp * NG;
  rank[e] = atomicAdd(&deg[segb + ep[el]], 1);
}

// ------- hierarchical scan: A) tile scan, B) partials, C) add prefix ------
__global__ __launch_bounds__(256) void scanA_kernel(
    const int* __restrict__ deg, int* __restrict__ offsets,
    int* __restrict__ tile_tot, int n) {
  __shared__ int wtot[4];
  const int t = threadIdx.x;
  const int base = blockIdx.x * 2048 + t * 8;
  int v[8], pre[8], s = 0;
#pragma unroll
  for (int j = 0; j < 8; ++j) {
    v[j] = (base + j < n) ? deg[base + j] : 0;
    pre[j] = s;
    s += v[j];
  }
  const int lane = t & 63, wv = t >> 6;
  int x = s;
#pragma unroll
  for (int o = 1; o < 64; o <<= 1) {
    int u = __shfl_up(x, o, 64);
    if (lane >= o) x += u;
  }
  if (lane == 63) wtot[wv] = x;
  __syncthreads();
  int wpre = 0;
#pragma unroll
  for (int j = 0; j < 4; ++j) wpre += (j < wv) ? wtot[j] : 0;
  int excl = wpre + x - s;
#pragma unroll
  for (int j = 0; j < 8; ++j)
    if (base + j < n) offsets[base + j] = excl + pre[j];
  if (t == 255) tile_tot[blockIdx.x] = wpre + x;
}

__global__ __launch_bounds__(256) void scanB_kernel(
    const int* __restrict__ tile_tot, int* __restrict__ tile_pre,
    int* __restrict__ offsets, int T, int n) {
  __shared__ int wtot[4];
  const int t = threadIdx.x;
  int v = (t < T) ? tile_tot[t] : 0;
  const int lane = t & 63, wv = t >> 6;
  int x = v;
#pragma unroll
  for (int o = 1; o < 64; o <<= 1) {
    int u = __shfl_up(x, o, 64);
    if (lane >= o) x += u;
  }
  if (lane == 63) wtot[wv] = x;
  __syncthreads();
  int wpre = 0;
#pragma unroll
  for (int j = 0; j < 4; ++j) wpre += (j < wv) ? wtot[j] : 0;
  if (t < T) tile_pre[t] = wpre + x - v;
  if (t == 255) offsets[n] = wpre + x;  // grand total
}

__global__ __launch_bounds__(256) void scanC_kernel(
    int* __restrict__ offsets, const int* __restrict__ tile_pre, int n) {
  const int add = tile_pre[blockIdx.x];
  const int base = blockIdx.x * 2048 + threadIdx.x * 8;
#pragma unroll
  for (int j = 0; j < 8; ++j)
    if (base + j < n) offsets[base + j] += add;
}

// ------- scatter3: pos = offsets[node] + rank[e]; dst only, no atomics ----
__global__ __launch_bounds__(256) void scatter3_kernel(
    const int* __restrict__ e0, const int* __restrict__ e1,
    const int* __restrict__ e2, const int* __restrict__ rank,
    const int* __restrict__ offsets, int* __restrict__ dst_s,
    int E, int NG) {
  int e = blockIdx.x * 256 + threadIdx.x;
  if (e >= 3 * E) return;
  int mp = (e >= 2 * E) ? 2 : ((e >= E) ? 1 : 0);
  int el = e - mp * E;
  const int* ep = (mp == 0) ? e0 : (mp == 1) ? e1 : e2;
  int s = ep[el], d = ep[el + E];
  int hb = (mp == 2) ? 2 * NG : mp * NG;
  dst_s[offsets[hb + s] + rank[e]] = d;
}

// ------- fused gather + logits + relation combine: wave per OUTPUT node ---
// Record phase: 64 lanes load 64 dst ids, gather tr3, compute ex in parallel.
// Edge phase: half-wave rows (32 lanes x 8B), 2 edges per wave-iteration,
// 2-wide unroll; trip counts wave-uniform, tail via clamp + weight-zero so
// every shuffle runs with the full wave active.
__global__ __launch_bounds__(256) void gather_combine(
    const ushort* __restrict__ rb_gene, const ushort* __restrict__ rb_prot,
    const ushort* __restrict__ lb_gene, const ushort* __restrict__ lb_prot,
    const int* __restrict__ offsets, const int* __restrict__ dst_s,
    const float* __restrict__ tl3, const float* __restrict__ tr3,
    const float* __restrict__ sharp,
    const float* __restrict__ cgW, const float* __restrict__ cgb,
    const float* __restrict__ cpW, const float* __restrict__ cpb,
    float* __restrict__ out_gene, float* __restrict__ out_prot,
    int NG, int NP) {
  const int lane = threadIdx.x & 63;
  const int half = lane >> 5;
  const int l32 = lane & 31;
  const int node = blockIdx.x * 4 + (threadIdx.x >> 6);
  if (node >= NG + NP) return;
  const bool isGene = node < NG;

  float a0[4] = {0.f, 0.f, 0.f, 0.f};
  float a1[4] = {0.f, 0.f, 0.f, 0.f};
  float ds0 = 0.f, ds1 = 0.f;

  for (int r = 0; r < 2; ++r) {
    if (r == 1 && !isGene) break;
    const int h = (isGene && r == 0) ? node : NG + node;     // concat head id
    const int tb = isGene ? (r == 0 ? 0 : NG) : NG + NP;     // tr3 seg base
    const ushort* rt = (isGene && r == 0) ? rb_gene : rb_prot;
    const float tlv = tl3[h];                                // wave-uniform
    const float shv = sharp[isGene ? r : 2];
    const int j0 = offsets[h], j1 = offsets[h + 1];

    float ac0 = 0.f, ac1 = 0.f, ac2 = 0.f, ac3 = 0.f, ds = 0.f;
    for (int bj = j0; bj < j1; bj += 64) {
      const int cc = min(64, j1 - bj);
      int myd = 0;
      float myex = 0.f;
      if (lane < cc) {
        myd = dst_s[bj + lane];
        // |tl+tr| <= sum|qw| ~ 10 -> exp safe in fp32 without max-shift.
        myex = expf((tlv + tr3[tb + myd]) * shv);
        ds += myex;
      }
      const int kmax = (cc + 1) >> 1;       // edge-pairs in this chunk
      for (int k = 0; k < kmax; k += 2) {   // 2 pairs (4 edges) per iter
        int i0 = (k << 1) | half;
        int i1 = ((k + 1) << 1) | half;
        int c0 = (i0 < cc) ? i0 : 0;
        int c1 = (i1 < cc) ? i1 : 0;
        int d0 = __shfl(myd, c0, 64);
        float w0 = __shfl(myex, c0, 64);
        int d1 = __shfl(myd, c1, 64);
        float w1 = __shfl(myex, c1, 64);
        w0 = (i0 < cc) ? w0 : 0.f;
        w1 = (i1 < cc) ? w1 : 0.f;
        uint2 v0 = *(const uint2*)(rt + (size_t)d0 * 128 + l32 * 4);
        uint2 v1 = *(const uint2*)(rt + (size_t)d1 * 128 + l32 * 4);
        ac0 += b2f_lo(v0.x) * w0 + b2f_lo(v1.x) * w1;
        ac1 += b2f_hi(v0.x) * w0 + b2f_hi(v1.x) * w1;
        ac2 += b2f_lo(v0.y) * w0 + b2f_lo(v1.y) * w1;
        ac3 += b2f_hi(v0.y) * w0 + b2f_hi(v1.y) * w1;
      }
    }
    if (r == 0) { a0[0] = ac0; a0[1] = ac1; a0[2] = ac2; a0[3] = ac3; ds0 = ds; }
    else        { a1[0] = ac0; a1[1] = ac1; a1[2] = ac2; a1[3] = ac3; ds1 = ds; }
  }

  // fold halves (each half holds its own edges' partial sums for cols l32*4..)
#pragma unroll
  for (int c = 0; c < 4; ++c) {
    a0[c] += __shfl_xor(a0[c], 32, 64);
    a1[c] += __shfl_xor(a1[c], 32, 64);
  }
#pragma unroll
  for (int m = 32; m >= 1; m >>= 1) {
    ds0 += __shfl_xor(ds0, m, 64);
    ds1 += __shfl_xor(ds1, m, 64);
  }
  const float inv0 = 1.f / (ds0 + 1e-16f);
  const float inv1 = 1.f / (ds1 + 1e-16f);
  float g0[4], g1[4], self[4];
#pragma unroll
  for (int c = 0; c < 4; ++c) { g0[c] = a0[c] * inv0; g1[c] = a1[c] * inv1; }
  {
    const ushort* lbp = isGene ? lb_gene + (size_t)node * 128
                               : lb_prot + (size_t)(node - NG) * 128;
    uint2 sv = *(const uint2*)(lbp + l32 * 4);
    self[0] = b2f_lo(sv.x); self[1] = b2f_hi(sv.x);
    self[2] = b2f_lo(sv.y); self[3] = b2f_hi(sv.y);
  }

  const float* cW = isGene ? cgW : cpW;
  const float cb = isGene ? cgb[0] : cpb[0];
  const float4 w4 = *(const float4*)(cW + l32 * 4);
  float p0 = g0[0] * w4.x + g0[1] * w4.y + g0[2] * w4.z + g0[3] * w4.w;
  float p1 = g1[0] * w4.x + g1[1] * w4.y + g1[2] * w4.z + g1[3] * w4.w;
  float ps = self[0] * w4.x + self[1] * w4.y + self[2] * w4.z + self[3] * w4.w;
#pragma unroll
  for (int m = 16; m >= 1; m >>= 1) {  // halves duplicate; reduce 32 cols
    p0 += __shfl_xor(p0, m, 64);
    p1 += __shfl_xor(p1, m, 64);
    ps += __shfl_xor(ps, m, 64);
  }
  const float s0 = p0 + cb, s1 = p1 + cb, ss = ps + cb;
  const float mx = isGene ? fmaxf(fmaxf(s0, s1), ss) : fmaxf(s0, ss);
  const float e0 = expf(s0 - mx);
  const float e1 = isGene ? expf(s1 - mx) : 0.f;
  const float es = expf(ss - mx);
  const float sum = e0 + e1 + es;
  const float b0 = e0 / sum, b1 = e1 / sum, bs = es / sum;

  if (half == 0) {
    float4 o;
    o.x = fmaxf(g0[0] * b0 + g1[0] * b1 + self[0] * bs, 0.f);
    o.y = fmaxf(g0[1] * b0 + g1[1] * b1 + self[1] * bs, 0.f);
    o.z = fmaxf(g0[2] * b0 + g1[2] * b1 + self[2] * bs, 0.f);
    o.w = fmaxf(g0[3] * b0 + g1[3] * b1 + self[3] * bs, 0.f);
    float* op = isGene ? out_gene + (size_t)node * 128
                       : out_prot + (size_t)(node - NG) * 128;
    *(float4*)(op + l32 * 4) = o;
  }
}

// ---------------------------------------------------------------------------
extern "C" void kernel_launch(void* const* d_in, const int* in_sizes, int n_in,
                              void* d_out, int out_size, void* d_ws,
                              size_t ws_size, hipStream_t stream) {
  const float* x_gene  = (const float*)d_in[0];
  const float* x_prot  = (const float*)d_in[1];
  const float* Wl_gene = (const float*)d_in[2];
  const float* bl_gene = (const float*)d_in[3];
  const float* Wr_gene = (const float*)d_in[4];
  const float* br_gene = (const float*)d_in[5];
  const float* Wl_prot = (const float*)d_in[6];
  const float* bl_prot = (const float*)d_in[7];
  const float* Wr_prot = (const float*)d_in[8];
  const float* br_prot = (const float*)d_in[9];
  const float* alW     = (const float*)d_in[10];  // [3,32,128] contiguous
  const float* alb     = (const float*)d_in[11];  // [3,32] contiguous
  const float* arW     = (const float*)d_in[12];
  const float* arb     = (const float*)d_in[13];
  const float* qw      = (const float*)d_in[14];  // [3,64,1]
  const float* sharp   = (const float*)d_in[15];
  const float* cgW     = (const float*)d_in[16];
  const float* cgb     = (const float*)d_in[17];
  const float* cpW     = (const float*)d_in[18];
  const float* cpb     = (const float*)d_in[19];
  const int* e_gg      = (const int*)d_in[20];
  const int* e_gp      = (const int*)d_in[21];
  const int* e_pp      = (const int*)d_in[22];

  const int NG = in_sizes[0] / 256;
  const int NP = in_sizes[1] / 256;
  const int E  = in_sizes[20] / 2;
  const int NPG = (NG + 127) & ~127;
  const int NPP = (NP + 127) & ~127;
  const int NT = 2 * NG + NP;          // concatenated head-node space
  const int NR = NG + 2 * NP;          // concatenated tail-node space (tr)

  char* base = (char*)d_ws;
  size_t off = 0;
  auto alloc = [&](size_t bytes) {
    void* p = base + off;
    off = (off + bytes + 255) & ~(size_t)255;
    return p;
  };
  ushort* xb_gene = (ushort*)alloc((size_t)NPG * 256 * 2);
  ushort* xb_prot = (ushort*)alloc((size_t)NPP * 256 * 2);
  // aliases over xb region (valid after proj phase; 96*4=384 < 512 B/row)
  float* al_gene = (float*)xb_gene;                 // [NPG,64] = al0|al1
  float* ar_gene = al_gene + (size_t)NPG * 64;      // [NPG,32]
  float* al_prot = ar_gene + (size_t)NPG * 32;      // [NPP,32]
  float* ar_prot = al_prot + (size_t)NPP * 32;      // [NPP,64] = ar1|ar2

  ushort* Wlr_gene = (ushort*)alloc(256 * 256 * 2);
  ushort* Wlr_prot = (ushort*)alloc(256 * 256 * 2);
  ushort* alWb     = (ushort*)alloc(96 * 128 * 2);
  ushort* arWb     = (ushort*)alloc(96 * 128 * 2);
  ushort* lb_gene  = (ushort*)alloc((size_t)NPG * 128 * 2);
  ushort* rb_gene  = (ushort*)alloc((size_t)NPG * 128 * 2);
  ushort* lb_prot  = (ushort*)alloc((size_t)NPP * 128 * 2);
  ushort* rb_prot  = (ushort*)alloc((size_t)NPP * 128 * 2);
  int*    deg      = (int*)alloc((size_t)NT * 4);
  int*    offsets  = (int*)alloc((size_t)(NT + 1) * 4);
  const int TILES  = (NT + 2047) / 2048;
  int*    tile_tot = (int*)alloc((size_t)TILES * 4);
  int*    tile_pre = (int*)alloc((size_t)TILES * 4);
  int*    rank     = (int*)alloc((size_t)(3 * E) * 4);
  int*    dst_s    = (int*)alloc((size_t)(3 * E) * 4);
  float*  tl3      = (float*)alloc((size_t)NT * 4);
  float*  tr3      = (float*)alloc((size_t)NR * 4);

  float* out_gene = (float*)d_out;
  float* out_prot = out_gene + (size_t)NG * 128;

  dim3 blk(256);

  // ---- 0) batched bf16 conversions (1 dispatch) ----
  {
    CvtArgs a;
    const float* srcs[8] = {x_gene, x_prot, Wl_gene, Wr_gene, Wl_prot, Wr_prot, alW, arW};
    ushort* dsts[8] = {xb_gene, xb_prot, Wlr_gene, Wlr_gene + 128 * 256,
                       Wlr_prot, Wlr_prot + 128 * 256, alWb, arWb};
    int valids[8] = {NG * 256, NP * 256, 128 * 256, 128 * 256, 128 * 256, 128 * 256, 96 * 128, 96 * 128};
    int totals[8] = {NPG * 256, NPP * 256, 128 * 256, 128 * 256, 128 * 256, 128 * 256, 96 * 128, 96 * 128};
    int b = 0;
    for (int j = 0; j < 8; ++j) {
      a.src[j] = srcs[j]; a.dst[j] = dsts[j];
      a.valid[j] = valids[j]; a.total[j] = totals[j];
      a.bstart[j] = b;
      b += (totals[j] / 4 + 255) / 256;
    }
    a.bstart[8] = b;
    cvt_multi<<<b, blk, 0, stream>>>(a);
  }

  // ---- 1) fused l/r projections, both node types (1 dispatch) ----
  {
    ProjArgs p;
    p.xb[0] = xb_gene; p.xb[1] = xb_prot;
    p.Wb[0] = Wlr_gene; p.Wb[1] = Wlr_prot;
    p.bl[0] = bl_gene; p.bl[1] = bl_prot;
    p.br[0] = br_gene; p.br[1] = br_prot;
    p.lb[0] = lb_gene; p.lb[1] = lb_prot;
    p.rb[0] = rb_gene; p.rb[1] = rb_prot;
    p.N[0] = NG; p.N[1] = NP;
    proj_lr_mfma<<<dim3(NPG / 128, 2, 2), blk, 0, stream>>>(p);
  }

  // ---- 2) batched attention projections (1 dispatch) ----
  {
    AttnArgs a;
    a.Ab[0] = lb_gene; a.Wb[0] = alWb;            a.bias[0] = alb;      a.out[0] = al_gene; a.N[0] = NG; a.BN[0] = 64;
    a.Ab[1] = rb_gene; a.Wb[1] = arWb;            a.bias[1] = arb;      a.out[1] = ar_gene; a.N[1] = NG; a.BN[1] = 32;
    a.Ab[2] = lb_prot; a.Wb[2] = alWb + 64 * 128; a.bias[2] = alb + 64; a.out[2] = al_prot; a.N[2] = NP; a.BN[2] = 32;
    a.Ab[3] = rb_prot; a.Wb[3] = arWb + 32 * 128; a.bias[3] = arb + 32; a.out[3] = ar_prot; a.N[3] = NP; a.BN[3] = 64;
    attn_proj_multi<<<dim3(NPG / 128, 4), blk, 0, stream>>>(a);
  }

  // ---- 3) batched per-node tanh-dot scalars (1 dispatch) ----
  {
    TanhArgs t;
    const float* as[6] = {al_gene, ar_gene, al_gene + 32, ar_prot, al_prot, ar_prot + 32};
    const float* qs[6] = {qw + 0, qw + 32, qw + 64, qw + 96, qw + 128, qw + 160};
    float* outs[6] = {tl3, tr3, tl3 + NG, tr3 + NG, tl3 + 2 * NG, tr3 + NG + NP};
    int strides[6] = {64, 32, 64, 64, 32, 64};
    int Ns[6] = {NG, NG, NG, NP, NP, NP};
    int b = 0;
    for (int j = 0; j < 6; ++j) {
      t.a[j] = as[j]; t.q[j] = qs[j]; t.out[j] = outs[j];
      t.stride[j] = strides[j]; t.N[j] = Ns[j];
      t.bstart[j] = b;
      b += (Ns[j] + 7) / 8;
    }
    t.bstart[6] = b;
    tanh_multi<<<b, blk, 0, stream>>>(t);
  }

  // ---- 4) CSR build (hist+rank -> scan -> scatter, no second atomic) ----
  const int gridE3 = (3 * E + 255) / 256;
  hipMemsetAsync(deg, 0, (size_t)NT * sizeof(int), stream);
  hist3_kernel<<<gridE3, blk, 0, stream>>>(e_gg, e_gp, e_pp, deg, rank, E, NG);
  scanA_kernel<<<TILES, blk, 0, stream>>>(deg, offsets, tile_tot, NT);
  scanB_kernel<<<1, blk, 0, stream>>>(tile_tot, tile_pre, offsets, TILES, NT);
  scanC_kernel<<<TILES, blk, 0, stream>>>(offsets, tile_pre, NT);
  scatter3_kernel<<<gridE3, blk, 0, stream>>>(e_gg, e_gp, e_pp, rank, offsets, dst_s, E, NG);

  // ---- 5) fused gather + logits + relation combine (1 dispatch) ----
  gather_combine<<<(NG + NP + 3) / 4, blk, 0, stream>>>(
      rb_gene, rb_prot, lb_gene, lb_prot, offsets, dst_s, tl3, tr3, sharp,
      cgW, cgb, cpW, cpb, out_gene, out_prot, NG, NP);
}